// Round 5
// baseline (406.140 us; speedup 1.0000x reference)
//
#include <hip/hip_runtime.h>

#define RSQRT_D 0.08838834764831843f

__device__ __forceinline__ float rlane(float v, int l) {
    return __int_as_float(__builtin_amdgcn_readlane(__float_as_int(v), l));
}

// ============ Stage 1: polyline layer-1 (blk<512) + agent MLP (blk>=512) ============
__global__ __launch_bounds__(256) void k_stage1(
    const float* __restrict__ poly,
    const float* __restrict__ pm_w1, const float* __restrict__ pm_b1,
    const float* __restrict__ astate, const float* __restrict__ amask,
    const float* __restrict__ ae_w1, const float* __restrict__ ae_b1,
    const float* __restrict__ ae_w2, const float* __restrict__ ae_b2,
    const float* __restrict__ ae_w3, const float* __restrict__ ae_b3,
    const float* __restrict__ mr_w1,
    float* __restrict__ h1g, float* __restrict__ center,
    float* __restrict__ a_emb, float* __restrict__ pr)
{
    int blk = blockIdx.x;
    int t = threadIdx.x;
    if (blk < 512) {
        int bm = blk;
        int h = t & 127, lp = t >> 7;
        const float* pp = poly + bm*40;
        float w1x = pm_w1[h], w1y = pm_w1[128+h], b1 = pm_b1[h];
        #pragma unroll
        for (int u = 0; u < 10; ++u) {
            int l = lp*10 + u;
            float x = pp[2*l], y = pp[2*l+1];       // s_load (uniform)
            h1g[(bm*20+l)*128 + h] = fmaxf(fmaf(w1x,x,fmaf(w1y,y,b1)), 0.f);
        }
        if (t == 0) {
            float sx=0.f, sy=0.f;
            #pragma unroll
            for (int l=0;l<20;++l){ sx+=pp[2*l]; sy+=pp[2*l+1]; }
            center[bm*2+0]=sx*(1.f/20.f); center[bm*2+1]=sy*(1.f/20.f);
        }
    } else {
        // wave = one agent row; lane holds outputs h=lam and h=64+lam
        int r = (blk-512)*4 + (t>>6);
        int lam = t & 63;
        const float* st = astate + r*5;              // s_load (uniform)
        float px=st[0], py=st[1], pz=st[2], vx=st[3], vy=st[4];
        // pr[r][hh] = px*mr_w1[0][hh] + py*mr_w1[1][hh]  (rel-MLP agent part)
        pr[r*128+lam]    = fmaf(px, mr_w1[lam],    py*mr_w1[128+lam]);
        pr[r*128+64+lam] = fmaf(px, mr_w1[64+lam], py*mr_w1[192+lam]);
        // layer 1 (K=5)
        float a0 = ae_b1[lam], a1 = ae_b1[64+lam];
        a0 = fmaf(px, ae_w1[lam], a0);      a1 = fmaf(px, ae_w1[64+lam], a1);
        a0 = fmaf(py, ae_w1[128+lam], a0);  a1 = fmaf(py, ae_w1[192+lam], a1);
        a0 = fmaf(pz, ae_w1[256+lam], a0);  a1 = fmaf(pz, ae_w1[320+lam], a1);
        a0 = fmaf(vx, ae_w1[384+lam], a0);  a1 = fmaf(vx, ae_w1[448+lam], a1);
        a0 = fmaf(vy, ae_w1[512+lam], a0);  a1 = fmaf(vy, ae_w1[576+lam], a1);
        a0 = fmaxf(a0,0.f); a1 = fmaxf(a1,0.f);
        // layer 2 (in-register readlane broadcast)
        float c0 = ae_b2[lam], c1 = ae_b2[64+lam];
        #pragma unroll
        for (int k=0;k<64;++k){ float xk=rlane(a0,k);
            c0=fmaf(xk, ae_w2[k*128+lam], c0); c1=fmaf(xk, ae_w2[k*128+64+lam], c1); }
        #pragma unroll
        for (int k=0;k<64;++k){ float xk=rlane(a1,k);
            c0=fmaf(xk, ae_w2[(64+k)*128+lam], c0); c1=fmaf(xk, ae_w2[(64+k)*128+64+lam], c1); }
        c0=fmaxf(c0,0.f); c1=fmaxf(c1,0.f);
        // layer 3
        float d0 = ae_b3[lam], d1 = ae_b3[64+lam];
        #pragma unroll
        for (int k=0;k<64;++k){ float xk=rlane(c0,k);
            d0=fmaf(xk, ae_w3[k*128+lam], d0); d1=fmaf(xk, ae_w3[k*128+64+lam], d1); }
        #pragma unroll
        for (int k=0;k<64;++k){ float xk=rlane(c1,k);
            d0=fmaf(xk, ae_w3[(64+k)*128+lam], d0); d1=fmaf(xk, ae_w3[(64+k)*128+64+lam], d1); }
        float mk = (amask[r] > 0.5f) ? 1.f : 0.f;
        a_emb[r*128+lam]    = d0*mk;
        a_emb[r*128+64+lam] = d1*mk;
    }
}

// ============ Stage 2: polyline layer-2 + max + embeds + mo MLP + cm precompute ============
__global__ __launch_bounds__(256) void k_stage2(
    const float* __restrict__ h1g, const float* __restrict__ center,
    const float* __restrict__ pmask,
    const int* __restrict__ ptype, const int* __restrict__ ptl, const int* __restrict__ proute,
    const float* __restrict__ pm_w2, const float* __restrict__ pm_b2,
    const float* __restrict__ type_emb, const float* __restrict__ tl_emb, const float* __restrict__ route_emb,
    const float* __restrict__ mo_w1, const float* __restrict__ mo_b1,
    const float* __restrict__ mo_w2, const float* __restrict__ mo_b2,
    const float* __restrict__ mr_w1, const float* __restrict__ mr_b1,
    float* __restrict__ map_node, float* __restrict__ map_nodeT,
    float* __restrict__ cm)
{
    int bm = blockIdx.x;
    int b = bm >> 8, m = bm & 255;
    int t = threadIdx.x;
    int h = t & 127, lp = t >> 7;
    __shared__ float hvs[128];
    __shared__ float mxs[128];
    const float* hb = h1g + (bm*20 + lp*10)*128;     // 10 uniform s_load streams
    float acc[10];
    #pragma unroll
    for (int u=0;u<10;++u) acc[u]=0.f;
    #pragma unroll 4
    for (int k=0;k<128;++k) {
        float w = pm_w2[k*128+h];
        #pragma unroll
        for (int u=0;u<10;++u) acc[u] = fmaf(hb[u*128+k], w, acc[u]);
    }
    float mx = acc[0];
    #pragma unroll
    for (int u=1;u<10;++u) mx = fmaxf(mx, acc[u]);
    if (lp == 1) {
        mxs[h] = mx;
        // cm[b][hh][m] = cx*w[0][hh] + cy*w[1][hh] + b1[hh]
        float cx = center[bm*2+0], cy = center[bm*2+1];
        cm[(b*128+h)*256 + m] = fmaf(cx, mr_w1[h], fmaf(cy, mr_w1[128+h], mr_b1[h]));
    }
    __syncthreads();
    if (lp == 0) {
        mx = fmaxf(mx, mxs[h]);
        float val = fmaxf(mx + pm_b2[h], 0.f);       // relu before max == max then relu (monotone)
        int ti = min(max(ptype[bm],0),3);
        int si = min(max(ptl[bm],0),7);
        int ri = min(max(proute[bm],0),1);
        hvs[h] = val + type_emb[ti*128+h] + tl_emb[si*128+h] + route_emb[ri*128+h];
    }
    __syncthreads();
    if (t < 64) {   // wave 0 runs the small mo MLP via in-register readlane
        int lam = t;
        float vlo = hvs[lam], vhi = hvs[64+lam];
        float a0 = mo_b1[lam], a1 = mo_b1[64+lam];
        #pragma unroll
        for (int k=0;k<64;++k){ float xk=rlane(vlo,k);
            a0=fmaf(xk,mo_w1[k*128+lam],a0); a1=fmaf(xk,mo_w1[k*128+64+lam],a1); }
        #pragma unroll
        for (int k=0;k<64;++k){ float xk=rlane(vhi,k);
            a0=fmaf(xk,mo_w1[(64+k)*128+lam],a0); a1=fmaf(xk,mo_w1[(64+k)*128+64+lam],a1); }
        a0=fmaxf(a0,0.f); a1=fmaxf(a1,0.f);
        float c0 = mo_b2[lam], c1 = mo_b2[64+lam];
        #pragma unroll
        for (int k=0;k<64;++k){ float xk=rlane(a0,k);
            c0=fmaf(xk,mo_w2[k*128+lam],c0); c1=fmaf(xk,mo_w2[k*128+64+lam],c1); }
        #pragma unroll
        for (int k=0;k<64;++k){ float xk=rlane(a1,k);
            c0=fmaf(xk,mo_w2[(64+k)*128+lam],c0); c1=fmaf(xk,mo_w2[(64+k)*128+64+lam],c1); }
        float mk = (pmask[bm]>0.5f)?1.f:0.f;
        c0*=mk; c1*=mk;
        map_node[bm*128+lam]=c0; map_node[bm*128+64+lam]=c1;
        map_nodeT[(b*128+lam)*256+m]=c0; map_nodeT[(b*128+64+lam)*256+m]=c1;
    }
}

// ============ Stage 3: map-attention logits (QK dot + decomposed rel-MLP) ============
__global__ __launch_bounds__(256) void k_mlogits(
    const float* __restrict__ astate, const float* __restrict__ pmask,
    const float* __restrict__ a_emb, const float* __restrict__ map_nodeT,
    const float* __restrict__ center, const float* __restrict__ cm,
    const float* __restrict__ pr,
    const float* __restrict__ mr_w1, const float* __restrict__ mr_w2, const float* __restrict__ mr_b2,
    float* __restrict__ lgm)
{
    int r0 = blockIdx.x*4;
    int b = r0 >> 10;
    int m = threadIdx.x;
    float cx = center[(b*256+m)*2+0], cy = center[(b*256+m)*2+1];
    float dd[4], dt[4], s[4];
    float b2c = mr_b2[0];
    #pragma unroll
    for (int r=0;r<4;++r) {
        float px = astate[(r0+r)*5+0], py = astate[(r0+r)*5+1];   // s_load
        float rx = cx-px, ry = cy-py;
        dd[r] = sqrtf(rx*rx+ry*ry);
        dt[r]=0.f; s[r]=b2c;
    }
    #pragma unroll 4
    for (int d=0; d<128; ++d) {
        float v = map_nodeT[(b*128+d)*256+m];                     // coalesced vload
        #pragma unroll
        for (int r=0;r<4;++r) dt[r] = fmaf(v, a_emb[(r0+r)*128+d], dt[r]);  // s_load
    }
    #pragma unroll 2
    for (int hh=0; hh<128; ++hh) {
        float cmv = cm[(b*128+hh)*256+m];                         // coalesced vload
        float wc = mr_w1[256+hh];                                 // s_load
        float w2 = mr_w2[hh];                                     // s_load
        #pragma unroll
        for (int r=0;r<4;++r) {
            float t1 = fmaf(dd[r], wc, cmv - pr[(r0+r)*128+hh]);  // s_load pr
            t1 = fmaxf(t1, 0.f);
            s[r] = fmaf(t1, w2, s[r]);
        }
    }
    bool ok = pmask[b*256+m] > 0.5f;
    #pragma unroll
    for (int r=0;r<4;++r)
        lgm[(r0+r)*256+m] = ok ? fmaf(dt[r], RSQRT_D, s[r]) : -1e30f;
}

// ============ Stage 4: map softmax+PV (blk<512) | neighbor logits+softmax (blk>=512) ============
__global__ __launch_bounds__(256) void k_stage4(
    const float* __restrict__ astate, const float* __restrict__ amask,
    const float* __restrict__ a_emb, const float* __restrict__ map_node,
    const float* __restrict__ lgm,
    const float* __restrict__ nr_w1, const float* __restrict__ nr_b1,
    const float* __restrict__ nr_w2, const float* __restrict__ nr_b2,
    float* __restrict__ map_ctx, float* __restrict__ p_n)
{
    int blk = blockIdx.x, t = threadIdx.x;
    int lam = t & 63, wv = t >> 6;
    if (blk < 512) {
        // wave = row r; lane holds m = 4*lam..4*lam+3
        int r = blk*4 + wv;
        int b = r >> 10;
        const float* lr = lgm + r*256;
        float4 xv = *(const float4*)(lr + lam*4);
        float mxv = fmaxf(fmaxf(xv.x,xv.y), fmaxf(xv.z,xv.w));
        for (int off=32; off; off>>=1) mxv = fmaxf(mxv, __shfl_xor(mxv, off));
        float e0 = (xv.x>-1e29f)?expf(xv.x-mxv):0.f;
        float e1 = (xv.y>-1e29f)?expf(xv.y-mxv):0.f;
        float e2 = (xv.z>-1e29f)?expf(xv.z-mxv):0.f;
        float e3 = (xv.w>-1e29f)?expf(xv.w-mxv):0.f;
        float sm = e0+e1+e2+e3;
        for (int off=32; off; off>>=1) sm += __shfl_xor(sm, off);
        float inv = 1.f/fmaxf(sm,1e-9f);
        float p0=e0*inv, p1=e1*inv, p2=e2*inv, p3=e3*inv;
        float o0=0.f, o1=0.f;
        const float* mn = map_node + b*256*128;
        #pragma unroll
        for (int mm=0; mm<256; ++mm) {
            float pm = rlane((mm&3)==0?p0:((mm&3)==1?p1:((mm&3)==2?p2:p3)), mm>>2);
            o0 = fmaf(pm, mn[mm*128+lam],    o0);
            o1 = fmaf(pm, mn[mm*128+64+lam], o1);
        }
        map_ctx[r*128+lam]=o0; map_ctx[r*128+64+lam]=o1;
    } else {
        // wave = 2 rows (r, r+1); half-wave = row; lane-within-half = j
        int blk2 = blk - 512;
        int hf = lam >> 5, j = lam & 31;
        int r = blk2*8 + wv*2 + hf;
        int b = r>>10, i = (r>>5)&31, tt = r&31;
        int rj = (b*32+j)*32+tt;
        float pxi = astate[r*5+0], pyi = astate[r*5+1], vxi = astate[r*5+3], vyi = astate[r*5+4];
        float pxj = astate[rj*5+0], pyj = astate[rj*5+1], vxj = astate[rj*5+3], vyj = astate[rj*5+4];
        float rpx = pxj-pxi, rpy=pyj-pyi, rvx=vxj-vxi, rvy=vyj-vyi;
        float dd = sqrtf(rpx*rpx+rpy*rpy);
        float acc = 0.f, dot = 0.f;
        #pragma unroll 2
        for (int hh=0; hh<128; ++hh) {
            float t1 = fmaf(rpx, nr_w1[hh], fmaf(rpy, nr_w1[128+hh],
                       fmaf(rvx, nr_w1[256+hh], fmaf(rvy, nr_w1[384+hh],
                       fmaf(dd, nr_w1[512+hh], nr_b1[hh])))));     // s_load weights
            t1 = fmaxf(t1, 0.f);
            acc = fmaf(t1, nr_w2[hh], acc);
            dot = fmaf(a_emb[r*128+hh], a_emb[rj*128+hh], dot);
        }
        bool vi = amask[r]>0.5f, vj = amask[rj]>0.5f;
        bool okn = vi && vj && (dd<=30.f) && (j!=i);
        float lg = okn ? fmaf(dot, RSQRT_D, acc + nr_b2[0]) : -1e30f;
        float mxv = lg;
        for (int off=16; off; off>>=1) mxv = fmaxf(mxv, __shfl_xor(mxv, off));
        float e = (lg>-1e29f)?expf(lg-mxv):0.f;
        float sm = e;
        for (int off=16; off; off>>=1) sm += __shfl_xor(sm, off);
        p_n[r*32+j] = e / fmaxf(sm,1e-9f);
    }
}

// ============ Stage 5: neighbor ctx + output MLP ============
// block 256 = 2 quads x 2 h-half waves; wave computes layer1 for its h-half of 4 rows
__global__ __launch_bounds__(256) void k_out(
    const float* __restrict__ amask, const float* __restrict__ a_emb,
    const float* __restrict__ map_ctx, const float* __restrict__ p_n,
    const float* __restrict__ to_w1, const float* __restrict__ to_b1,
    const float* __restrict__ to_w2, const float* __restrict__ to_b2,
    float* __restrict__ out)
{
    int t = threadIdx.x;
    int lam = t & 63, wv = t >> 6;
    int ql = wv >> 1, role = wv & 1;
    int q = blockIdx.x*2 + ql;
    int r0 = q*4;
    int b = r0 >> 10, t0 = r0 & 31;
    __shared__ float gx[2][4][128];
    // nbr ctx (both roles compute; lane holds d=lam and d=64+lam)
    float nc0[4]={0.f,0.f,0.f,0.f}, nc1[4]={0.f,0.f,0.f,0.f};
    for (int j=0;j<32;++j) {
        int rjb = (b*32+j)*32 + t0;
        #pragma unroll
        for (int rr=0;rr<4;++rr) {
            float pj = p_n[(r0+rr)*32+j];                 // s_load
            const float* ej = a_emb + (rjb+rr)*128;
            nc0[rr] = fmaf(pj, ej[lam],    nc0[rr]);
            nc1[rr] = fmaf(pj, ej[64+lam], nc1[rr]);
        }
    }
    int hown = role*64 + lam;
    float acc[4];
    #pragma unroll
    for (int rr=0;rr<4;++rr) acc[rr] = to_b1[hown];
    #pragma unroll 2
    for (int k=0;k<128;++k) {
        float w = to_w1[k*128+hown];
        #pragma unroll
        for (int rr=0;rr<4;++rr) acc[rr] = fmaf(a_emb[(r0+rr)*128+k], w, acc[rr]);   // s_load
    }
    #pragma unroll 2
    for (int k=0;k<128;++k) {
        float w = to_w1[(128+k)*128+hown];
        #pragma unroll
        for (int rr=0;rr<4;++rr) acc[rr] = fmaf(map_ctx[(r0+rr)*128+k], w, acc[rr]); // s_load
    }
    #pragma unroll
    for (int k=0;k<64;++k) {
        float w = to_w1[(256+k)*128+hown];
        #pragma unroll
        for (int rr=0;rr<4;++rr) acc[rr] = fmaf(rlane(nc0[rr],k), w, acc[rr]);
    }
    #pragma unroll
    for (int k=0;k<64;++k) {
        float w = to_w1[(320+k)*128+hown];
        #pragma unroll
        for (int rr=0;rr<4;++rr) acc[rr] = fmaf(rlane(nc1[rr],k), w, acc[rr]);
    }
    #pragma unroll
    for (int rr=0;rr<4;++rr) gx[ql][rr][hown] = fmaxf(acc[rr], 0.f);
    __syncthreads();
    // layer 2: role 0 -> rows 0,1 ; role 1 -> rows 2,3 ; lane = output o
    #pragma unroll
    for (int rp=0; rp<2; ++rp) {
        int rr = role*2 + rp;
        float glo = gx[ql][rr][lam], ghi = gx[ql][rr][64+lam];
        float a2 = to_b2[lam];
        #pragma unroll
        for (int k=0;k<64;++k) a2 = fmaf(rlane(glo,k), to_w2[k*64+lam], a2);
        #pragma unroll
        for (int k=0;k<64;++k) a2 = fmaf(rlane(ghi,k), to_w2[(64+k)*64+lam], a2);
        float mk = (amask[r0+rr]>0.5f)?1.f:0.f;
        out[(r0+rr)*64+lam] = a2*mk;
    }
}

extern "C" void kernel_launch(void* const* d_in, const int* in_sizes, int n_in,
                              void* d_out, int out_size, void* d_ws, size_t ws_size,
                              hipStream_t stream) {
    const float* agents_state  = (const float*)d_in[0];
    const float* agents_mask   = (const float*)d_in[1];
    const float* map_polylines = (const float*)d_in[2];
    const float* map_poly_mask = (const float*)d_in[3];
    const int*   map_poly_type = (const int*)d_in[4];
    const int*   map_tl_status = (const int*)d_in[5];
    const int*   map_on_route  = (const int*)d_in[6];
    const float* pm_w1 = (const float*)d_in[7];
    const float* pm_b1 = (const float*)d_in[8];
    const float* pm_w2 = (const float*)d_in[9];
    const float* pm_b2 = (const float*)d_in[10];
    const float* type_emb  = (const float*)d_in[11];
    const float* tl_emb    = (const float*)d_in[12];
    const float* route_emb = (const float*)d_in[13];
    const float* mo_w1 = (const float*)d_in[14];
    const float* mo_b1 = (const float*)d_in[15];
    const float* mo_w2 = (const float*)d_in[16];
    const float* mo_b2 = (const float*)d_in[17];
    const float* ae_w1 = (const float*)d_in[18];
    const float* ae_b1 = (const float*)d_in[19];
    const float* ae_w2 = (const float*)d_in[20];
    const float* ae_b2 = (const float*)d_in[21];
    const float* ae_w3 = (const float*)d_in[22];
    const float* ae_b3 = (const float*)d_in[23];
    const float* mr_w1 = (const float*)d_in[24];
    const float* mr_b1 = (const float*)d_in[25];
    const float* mr_w2 = (const float*)d_in[26];
    const float* mr_b2 = (const float*)d_in[27];
    const float* nr_w1 = (const float*)d_in[28];
    const float* nr_b1 = (const float*)d_in[29];
    const float* nr_w2 = (const float*)d_in[30];
    const float* nr_b2 = (const float*)d_in[31];
    const float* to_w1 = (const float*)d_in[32];
    const float* to_b1 = (const float*)d_in[33];
    const float* to_w2 = (const float*)d_in[34];
    const float* to_b2 = (const float*)d_in[35];

    float* ws = (float*)d_ws;
    float* h1g      = ws;                    // 512*20*128 = 1310720
    float* map_node = ws + 1310720;          // 65536
    float* map_nodeT= ws + 1376256;          // 65536
    float* center   = ws + 1441792;          // 1024
    float* cm       = ws + 1442816;          // 65536
    float* a_emb    = ws + 1508352;          // 262144
    float* pr       = ws + 1770496;          // 262144
    float* lgm      = ws + 2032640;          // 524288 (16B-aligned)
    float* map_ctx  = ws + 2556928;          // 262144
    float* p_n      = ws + 2819072;          // 65536

    float* out = (float*)d_out;

    k_stage1<<<1024, 256, 0, stream>>>(map_polylines, pm_w1, pm_b1,
        agents_state, agents_mask, ae_w1, ae_b1, ae_w2, ae_b2, ae_w3, ae_b3,
        mr_w1, h1g, center, a_emb, pr);

    k_stage2<<<512, 256, 0, stream>>>(h1g, center, map_poly_mask,
        map_poly_type, map_tl_status, map_on_route,
        pm_w2, pm_b2, type_emb, tl_emb, route_emb,
        mo_w1, mo_b1, mo_w2, mo_b2, mr_w1, mr_b1,
        map_node, map_nodeT, cm);

    k_mlogits<<<512, 256, 0, stream>>>(agents_state, map_poly_mask,
        a_emb, map_nodeT, center, cm, pr, mr_w1, mr_w2, mr_b2, lgm);

    k_stage4<<<768, 256, 0, stream>>>(agents_state, agents_mask,
        a_emb, map_node, lgm, nr_w1, nr_b1, nr_w2, nr_b2, map_ctx, p_n);

    k_out<<<256, 256, 0, stream>>>(agents_mask, a_emb, map_ctx, p_n,
        to_w1, to_b1, to_w2, to_b2, out);
}

// Round 6
// 303.902 us; speedup vs baseline: 1.3364x; 1.3364x over previous
//
#include <hip/hip_runtime.h>

#define RSQRT_D 0.08838834764831843f

__device__ __forceinline__ float rl(float v, int l) {
    return __int_as_float(__builtin_amdgcn_readlane(__float_as_int(v), l));
}

// =====================================================================
// P1: blocks 0..511  -> map/polyline encoder (one block per (b,m))
//     blocks 512..639 -> agent MLP, 4 rows per wave (+ q/aT/posT tables)
// =====================================================================
__global__ __launch_bounds__(256) void k_p1(
    const float* __restrict__ poly, const float* __restrict__ pmask,
    const int* __restrict__ ptype, const int* __restrict__ ptl, const int* __restrict__ proute,
    const float* __restrict__ pm_w1, const float* __restrict__ pm_b1,
    const float* __restrict__ pm_w2, const float* __restrict__ pm_b2,
    const float* __restrict__ type_emb, const float* __restrict__ tl_emb, const float* __restrict__ route_emb,
    const float* __restrict__ mo_w1, const float* __restrict__ mo_b1,
    const float* __restrict__ mo_w2, const float* __restrict__ mo_b2,
    const float* __restrict__ mr_w1, const float* __restrict__ mr_b1,
    const float* __restrict__ astate, const float* __restrict__ amask,
    const float* __restrict__ ae_w1, const float* __restrict__ ae_b1,
    const float* __restrict__ ae_w2, const float* __restrict__ ae_b2,
    const float* __restrict__ ae_w3, const float* __restrict__ ae_b3,
    const float* __restrict__ nr_w1, const float* __restrict__ nr_b1,
    float* __restrict__ map_node, float* __restrict__ map_nodeT,
    float* __restrict__ cm, float* __restrict__ center,
    float* __restrict__ a_emb, float* __restrict__ aT,
    float* __restrict__ q2, float* __restrict__ qn, float* __restrict__ posT)
{
    int tid = threadIdx.x;
    int lam = tid & 63;
    __shared__ float red[20][128];
    __shared__ float xch[128];

    if (blockIdx.x < 512) {
        int bm = blockIdx.x;
        int b = bm >> 8, m = bm & 255;
        int h = tid & 127, lp = tid >> 7;
        // polyline points in lanes (lam<40 valid)
        int pidx = bm*40 + lam; if (pidx > 20479) pidx = 20479;
        float ptreg = poly[pidx];
        // layer1 values for unit x = lp*64+lam, all 20 points
        int x = lp*64 + lam;
        float w1x = pm_w1[x], w1y = pm_w1[128+x], b1v = pm_b1[x];
        float h1r[20];
        #pragma unroll
        for (int l = 0; l < 20; ++l) {
            float xl = rl(ptreg, 2*l), yl = rl(ptreg, 2*l+1);
            h1r[l] = fmaxf(fmaf(w1x, xl, fmaf(w1y, yl, b1v)), 0.f);
        }
        // layer2 partial over k-range [lp*64, lp*64+64)
        float acc[20];
        #pragma unroll
        for (int l = 0; l < 20; ++l) acc[l] = 0.f;
        #pragma unroll
        for (int kk = 0; kk < 64; ++kk) {
            float w = pm_w2[(lp*64+kk)*128 + h];
            #pragma unroll
            for (int l = 0; l < 20; ++l) acc[l] = fmaf(rl(h1r[l], kk), w, acc[l]);
        }
        if (lp == 1) {
            #pragma unroll
            for (int l = 0; l < 20; ++l) red[l][h] = acc[l];
        }
        __syncthreads();
        if (lp == 0) {
            float mx = -1e30f;
            #pragma unroll
            for (int l = 0; l < 20; ++l) mx = fmaxf(mx, acc[l] + red[l][h]);
            mx = fmaxf(mx + pm_b2[h], 0.f);   // relu(max+b) == max(relu) since b common, relu monotone
            int ti = min(max(ptype[bm],0),3);
            int si = min(max(ptl[bm],0),7);
            int ri = min(max(proute[bm],0),1);
            xch[h] = mx + type_emb[ti*128+h] + tl_emb[si*128+h] + route_emb[ri*128+h];
        }
        __syncthreads();
        // mo layer1: k split by lp
        float src = xch[lp*64 + lam];
        float a1p = 0.f;
        #pragma unroll
        for (int kk = 0; kk < 64; ++kk)
            a1p = fmaf(rl(src, kk), mo_w1[(lp*64+kk)*128 + h], a1p);
        if (lp == 1) red[0][h] = a1p;
        __syncthreads();
        if (lp == 0) {
            float a1v = fmaxf(a1p + red[0][h] + mo_b1[h], 0.f);
            red[1][h] = a1v;    // stage next-layer input in a fresh slot
        }
        __syncthreads();
        float src2 = red[1][lp*64 + lam];
        float a2p = 0.f;
        #pragma unroll
        for (int kk = 0; kk < 64; ++kk)
            a2p = fmaf(rl(src2, kk), mo_w2[(lp*64+kk)*128 + h], a2p);
        if (lp == 1) red[2][h] = a2p;
        __syncthreads();
        // center (uniform across threads via readlane sums)
        float sx = 0.f, sy = 0.f;
        #pragma unroll
        for (int l = 0; l < 20; ++l) { sx += rl(ptreg, 2*l); sy += rl(ptreg, 2*l+1); }
        sx *= 0.05f; sy *= 0.05f;
        if (lp == 0) {
            float val = a2p + red[2][h] + mo_b2[h];
            float mk = (pmask[bm] > 0.5f) ? 1.f : 0.f;
            val *= mk;
            map_node[bm*128 + h] = val;
            map_nodeT[(b*128+h)*256 + m] = val;
            cm[(b*128+h)*256 + m] = fmaf(sx, mr_w1[h], fmaf(sy, mr_w1[128+h], mr_b1[h]));
            if (h == 0) { center[bm*2+0] = sx; center[bm*2+1] = sy; }
        }
    } else {
        // ---------------- agent MLP: wave = 4 rows ----------------
        int qw = (blockIdx.x - 512)*4 + (tid >> 6);
        int r0b = qw * 4;
        int aidx = r0b*5 + lam; if (aidx > 10239) aidx = 10239;
        float streg = astate[aidx];
        float w1l[5], w1h[5];
        #pragma unroll
        for (int c = 0; c < 5; ++c) { w1l[c] = ae_w1[c*128+lam]; w1h[c] = ae_w1[c*128+64+lam]; }
        float b1l = ae_b1[lam], b1h = ae_b1[64+lam];
        float a1lo[4], a1hi[4];
        #pragma unroll
        for (int r = 0; r < 4; ++r) {
            float px = rl(streg, r*5+0), py = rl(streg, r*5+1), pz = rl(streg, r*5+2);
            float vx = rl(streg, r*5+3), vy = rl(streg, r*5+4);
            float lo = b1l, hi = b1h;
            lo = fmaf(px,w1l[0],lo); hi = fmaf(px,w1h[0],hi);
            lo = fmaf(py,w1l[1],lo); hi = fmaf(py,w1h[1],hi);
            lo = fmaf(pz,w1l[2],lo); hi = fmaf(pz,w1h[2],hi);
            lo = fmaf(vx,w1l[3],lo); hi = fmaf(vx,w1h[3],hi);
            lo = fmaf(vy,w1l[4],lo); hi = fmaf(vy,w1h[4],hi);
            a1lo[r] = fmaxf(lo, 0.f); a1hi[r] = fmaxf(hi, 0.f);
        }
        // layer2
        float c0[4], c1[4];
        {
            float b2l = ae_b2[lam], b2h = ae_b2[64+lam];
            #pragma unroll
            for (int r = 0; r < 4; ++r) { c0[r] = b2l; c1[r] = b2h; }
        }
        #pragma unroll
        for (int k = 0; k < 64; ++k) {
            float wl = ae_w2[k*128+lam], wh = ae_w2[k*128+64+lam];
            #pragma unroll
            for (int r = 0; r < 4; ++r) { float xv = rl(a1lo[r], k); c0[r]=fmaf(xv,wl,c0[r]); c1[r]=fmaf(xv,wh,c1[r]); }
        }
        #pragma unroll
        for (int k = 0; k < 64; ++k) {
            float wl = ae_w2[(64+k)*128+lam], wh = ae_w2[(64+k)*128+64+lam];
            #pragma unroll
            for (int r = 0; r < 4; ++r) { float xv = rl(a1hi[r], k); c0[r]=fmaf(xv,wl,c0[r]); c1[r]=fmaf(xv,wh,c1[r]); }
        }
        #pragma unroll
        for (int r = 0; r < 4; ++r) { a1lo[r] = fmaxf(c0[r],0.f); a1hi[r] = fmaxf(c1[r],0.f); }
        // layer3
        {
            float b3l = ae_b3[lam], b3h = ae_b3[64+lam];
            #pragma unroll
            for (int r = 0; r < 4; ++r) { c0[r] = b3l; c1[r] = b3h; }
        }
        #pragma unroll
        for (int k = 0; k < 64; ++k) {
            float wl = ae_w3[k*128+lam], wh = ae_w3[k*128+64+lam];
            #pragma unroll
            for (int r = 0; r < 4; ++r) { float xv = rl(a1lo[r], k); c0[r]=fmaf(xv,wl,c0[r]); c1[r]=fmaf(xv,wh,c1[r]); }
        }
        #pragma unroll
        for (int k = 0; k < 64; ++k) {
            float wl = ae_w3[(64+k)*128+lam], wh = ae_w3[(64+k)*128+64+lam];
            #pragma unroll
            for (int r = 0; r < 4; ++r) { float xv = rl(a1hi[r], k); c0[r]=fmaf(xv,wl,c0[r]); c1[r]=fmaf(xv,wh,c1[r]); }
        }
        // neighbor q-table weights
        float nA_l = nr_w1[lam],     nA_h = nr_w1[64+lam];
        float nB_l = nr_w1[128+lam], nB_h = nr_w1[192+lam];
        float nC_l = nr_w1[256+lam], nC_h = nr_w1[320+lam];
        float nD_l = nr_w1[384+lam], nD_h = nr_w1[448+lam];
        float nb_l = nr_b1[lam],     nb_h = nr_b1[64+lam];
        #pragma unroll
        for (int r = 0; r < 4; ++r) {
            int rr = r0b + r;
            float mk = (amask[rr] > 0.5f) ? 1.f : 0.f;
            float e0 = c0[r]*mk, e1 = c1[r]*mk;
            int bb = rr >> 10, nn = (rr >> 5) & 31, tt = rr & 31;
            int bt = bb*32 + tt;
            a_emb[rr*128 + lam]    = e0;
            a_emb[rr*128 + 64+lam] = e1;
            aT[(bt*128 + lam)*32 + nn]    = e0;
            aT[(bt*128 + 64+lam)*32 + nn] = e1;
            float px = rl(streg, r*5+0), py = rl(streg, r*5+1);
            float vx = rl(streg, r*5+3), vy = rl(streg, r*5+4);
            float ql = fmaf(px,nA_l,fmaf(py,nB_l,fmaf(vx,nC_l, vy*nD_l)));
            float qh = fmaf(px,nA_h,fmaf(py,nB_h,fmaf(vx,nC_h, vy*nD_h)));
            qn[rr*128 + lam]    = ql;
            qn[rr*128 + 64+lam] = qh;
            q2[(bt*128 + lam)*32 + nn]    = ql + nb_l;
            q2[(bt*128 + 64+lam)*32 + nn] = qh + nb_h;
            if (lam == 0) {
                posT[(bt*5+0)*32+nn] = px;
                posT[(bt*5+1)*32+nn] = py;
                posT[(bt*5+2)*32+nn] = vx;
                posT[(bt*5+3)*32+nn] = vy;
                posT[(bt*5+4)*32+nn] = amask[rr];
            }
        }
    }
}

// =====================================================================
// P2: blocks 0..511  -> map attention (logits + softmax + PV), 4 rows/block
//     blocks 512..767 -> neighbor attention (logits + softmax), 2 rows/wave
// =====================================================================
__global__ __launch_bounds__(256) void k_p2(
    const float* __restrict__ astate, const float* __restrict__ pmask,
    const float* __restrict__ a_emb, const float* __restrict__ map_node,
    const float* __restrict__ map_nodeT, const float* __restrict__ center,
    const float* __restrict__ cm,
    const float* __restrict__ mr_w1, const float* __restrict__ mr_w2, const float* __restrict__ mr_b2,
    const float* __restrict__ qn, const float* __restrict__ q2,
    const float* __restrict__ aT, const float* __restrict__ posT,
    const float* __restrict__ nr_w1, const float* __restrict__ nr_w2, const float* __restrict__ nr_b2,
    float* __restrict__ map_ctx, float* __restrict__ p_n)
{
    int tid = threadIdx.x;
    int lam = tid & 63, wv = tid >> 6;
    __shared__ float lg4[4][256];
    __shared__ __align__(16) float p4[256*4];
    __shared__ float ctxp[4][512];

    if (blockIdx.x < 512) {
        int r0 = blockIdx.x * 4;
        int b = r0 >> 10;
        int m = tid;
        int aidx = r0*5 + lam; if (aidx > 10239) aidx = 10239;
        float streg = astate[aidx];
        float wa_l = mr_w1[lam],     wa_h = mr_w1[64+lam];
        float wb_l = mr_w1[128+lam], wb_h = mr_w1[192+lam];
        float wc_l = mr_w1[256+lam], wc_h = mr_w1[320+lam];
        float w2_l = mr_w2[lam],     w2_h = mr_w2[64+lam];
        float b2c = mr_b2[0];
        float cx = center[(b*256+m)*2+0], cy = center[(b*256+m)*2+1];
        float prl[4], prh[4], eal[4], eah[4], dd[4], dt[4], sA[4];
        #pragma unroll
        for (int r = 0; r < 4; ++r) {
            float px = rl(streg, r*5+0), py = rl(streg, r*5+1);
            prl[r] = fmaf(px, wa_l, py*wb_l);
            prh[r] = fmaf(px, wa_h, py*wb_h);
            eal[r] = a_emb[(r0+r)*128 + lam];
            eah[r] = a_emb[(r0+r)*128 + 64+lam];
            float rx = cx - px, ry = cy - py;
            dd[r] = sqrtf(rx*rx + ry*ry);
            dt[r] = 0.f; sA[r] = b2c;
        }
        const float* mT  = map_nodeT + b*128*256 + m;
        const float* cmp = cm        + b*128*256 + m;
        #pragma unroll
        for (int d = 0; d < 64; ++d) {
            float v = mT[d*256];
            #pragma unroll
            for (int r = 0; r < 4; ++r) dt[r] = fmaf(v, rl(eal[r], d), dt[r]);
        }
        #pragma unroll
        for (int d = 0; d < 64; ++d) {
            float v = mT[(64+d)*256];
            #pragma unroll
            for (int r = 0; r < 4; ++r) dt[r] = fmaf(v, rl(eah[r], d), dt[r]);
        }
        #pragma unroll
        for (int hh = 0; hh < 64; ++hh) {
            float cmv = cmp[hh*256];
            float wcv = rl(wc_l, hh), w2v = rl(w2_l, hh);
            #pragma unroll
            for (int r = 0; r < 4; ++r) {
                float t1 = fmaf(dd[r], wcv, cmv - rl(prl[r], hh));
                sA[r] = fmaf(fmaxf(t1, 0.f), w2v, sA[r]);
            }
        }
        #pragma unroll
        for (int hh = 0; hh < 64; ++hh) {
            float cmv = cmp[(64+hh)*256];
            float wcv = rl(wc_h, hh), w2v = rl(w2_h, hh);
            #pragma unroll
            for (int r = 0; r < 4; ++r) {
                float t1 = fmaf(dd[r], wcv, cmv - rl(prh[r], hh));
                sA[r] = fmaf(fmaxf(t1, 0.f), w2v, sA[r]);
            }
        }
        bool mk = pmask[b*256+m] > 0.5f;
        #pragma unroll
        for (int r = 0; r < 4; ++r)
            lg4[r][m] = mk ? fmaf(dt[r], RSQRT_D, sA[r]) : -1e30f;
        __syncthreads();
        // softmax: wave wv owns row wv
        {
            float x0 = lg4[wv][lam], x1 = lg4[wv][64+lam], x2 = lg4[wv][128+lam], x3 = lg4[wv][192+lam];
            float mxv = fmaxf(fmaxf(x0,x1), fmaxf(x2,x3));
            #pragma unroll
            for (int off = 32; off; off >>= 1) mxv = fmaxf(mxv, __shfl_xor(mxv, off));
            float e0 = (x0 > -1e29f) ? expf(x0-mxv) : 0.f;
            float e1 = (x1 > -1e29f) ? expf(x1-mxv) : 0.f;
            float e2 = (x2 > -1e29f) ? expf(x2-mxv) : 0.f;
            float e3 = (x3 > -1e29f) ? expf(x3-mxv) : 0.f;
            float sm = e0+e1+e2+e3;
            #pragma unroll
            for (int off = 32; off; off >>= 1) sm += __shfl_xor(sm, off);
            float inv = 1.f / fmaxf(sm, 1e-9f);
            p4[(lam)*4     + wv] = e0*inv;
            p4[(64+lam)*4  + wv] = e1*inv;
            p4[(128+lam)*4 + wv] = e2*inv;
            p4[(192+lam)*4 + wv] = e3*inv;
        }
        __syncthreads();
        // PV: wave wv handles m-chunk [wv*64, wv*64+64) for all 4 rows
        {
            int m0 = wv*64;
            float4 pq = *(const float4*)&p4[(m0+lam)*4];
            float a0[4] = {0.f,0.f,0.f,0.f}, a1[4] = {0.f,0.f,0.f,0.f};
            const float* mn = map_node + (b*256 + m0)*128;
            #pragma unroll
            for (int mm = 0; mm < 64; ++mm) {
                float v0 = mn[mm*128 + lam], v1 = mn[mm*128 + 64+lam];
                float pp0 = rl(pq.x, mm), pp1 = rl(pq.y, mm), pp2 = rl(pq.z, mm), pp3 = rl(pq.w, mm);
                a0[0]=fmaf(pp0,v0,a0[0]); a1[0]=fmaf(pp0,v1,a1[0]);
                a0[1]=fmaf(pp1,v0,a0[1]); a1[1]=fmaf(pp1,v1,a1[1]);
                a0[2]=fmaf(pp2,v0,a0[2]); a1[2]=fmaf(pp2,v1,a1[2]);
                a0[3]=fmaf(pp3,v0,a0[3]); a1[3]=fmaf(pp3,v1,a1[3]);
            }
            #pragma unroll
            for (int r = 0; r < 4; ++r) { ctxp[wv][r*128+lam] = a0[r]; ctxp[wv][r*128+64+lam] = a1[r]; }
        }
        __syncthreads();
        for (int q = tid; q < 512; q += 256) {
            float s = ctxp[0][q] + ctxp[1][q] + ctxp[2][q] + ctxp[3][q];
            map_ctx[(r0 + (q>>7))*128 + (q & 127)] = s;
        }
    } else {
        // ---------------- neighbor attention: wave = rows (r0, r0+1) ----------------
        int beta = blockIdx.x - 512;
        int r0 = beta*8 + wv*2;
        int hf = lam >> 5, j = lam & 31;
        bool hfb = (hf == 1);
        int rr = r0 + hf;
        int b = rr >> 10, ii = (rr >> 5) & 31, tt = rr & 31;
        int bt = b*32 + tt;
        // VGPR tables
        float uqA_l = qn[r0*128+lam],     uqA_h = qn[r0*128+64+lam];
        float uqB_l = qn[(r0+1)*128+lam], uqB_h = qn[(r0+1)*128+64+lam];
        float eiA_l = a_emb[r0*128+lam],     eiA_h = a_emb[r0*128+64+lam];
        float eiB_l = a_emb[(r0+1)*128+lam], eiB_h = a_emb[(r0+1)*128+64+lam];
        float wE_l = nr_w1[512+lam], wE_h = nr_w1[576+lam];
        float w2_l = nr_w2[lam],     w2_h = nr_w2[64+lam];
        // per-lane j data
        float pxj = posT[(bt*5+0)*32 + j];
        float pyj = posT[(bt*5+1)*32 + j];
        float vxj = posT[(bt*5+2)*32 + j];
        float vyj = posT[(bt*5+3)*32 + j];
        float mj  = posT[(bt*5+4)*32 + j];
        float pxi = hfb ? rl(pxj, 32+ii) : rl(pxj, ii);
        float pyi = hfb ? rl(pyj, 32+ii) : rl(pyj, ii);
        float vxi = hfb ? rl(vxj, 32+ii) : rl(vxj, ii);
        float vyi = hfb ? rl(vyj, 32+ii) : rl(vyj, ii);
        float mi  = hfb ? rl(mj, 32+ii)  : rl(mj, ii);
        float rpx = pxj-pxi, rpy = pyj-pyi;
        float ddv = sqrtf(rpx*rpx + rpy*rpy);
        (void)vxi; (void)vyi;
        float s = nr_b2[0], dot = 0.f;
        const float* q2p = q2 + bt*128*32 + j;
        const float* aTp = aT + bt*128*32 + j;
        #pragma unroll
        for (int hh = 0; hh < 64; ++hh) {
            float qjv = q2p[hh*32];
            float ajv = aTp[hh*32];
            float qiv = hfb ? rl(uqB_l, hh) : rl(uqA_l, hh);
            float eiv = hfb ? rl(eiB_l, hh) : rl(eiA_l, hh);
            float t1 = fmaf(ddv, rl(wE_l, hh), qjv - qiv);
            s = fmaf(fmaxf(t1, 0.f), rl(w2_l, hh), s);
            dot = fmaf(eiv, ajv, dot);
        }
        #pragma unroll
        for (int hh = 0; hh < 64; ++hh) {
            float qjv = q2p[(64+hh)*32];
            float ajv = aTp[(64+hh)*32];
            float qiv = hfb ? rl(uqB_h, hh) : rl(uqA_h, hh);
            float eiv = hfb ? rl(eiB_h, hh) : rl(eiA_h, hh);
            float t1 = fmaf(ddv, rl(wE_h, hh), qjv - qiv);
            s = fmaf(fmaxf(t1, 0.f), rl(w2_h, hh), s);
            dot = fmaf(eiv, ajv, dot);
        }
        bool ok = (mi > 0.5f) && (mj > 0.5f) && (ddv <= 30.0f) && (j != ii);
        float lg = ok ? fmaf(dot, RSQRT_D, s) : -1e30f;
        float mxv = lg;
        #pragma unroll
        for (int off = 16; off; off >>= 1) mxv = fmaxf(mxv, __shfl_xor(mxv, off));
        float e = (lg > -1e29f) ? expf(lg - mxv) : 0.f;
        float sm = e;
        #pragma unroll
        for (int off = 16; off; off >>= 1) sm += __shfl_xor(sm, off);
        p_n[rr*32 + j] = e / fmaxf(sm, 1e-9f);
    }
}

// =====================================================================
// P3: neighbor ctx + output MLP. 256 blocks x 256 thr; wave = 2 rows.
// =====================================================================
__global__ __launch_bounds__(256) void k_p3(
    const float* __restrict__ amask, const float* __restrict__ a_emb,
    const float* __restrict__ map_ctx, const float* __restrict__ p_n,
    const float* __restrict__ to_w1, const float* __restrict__ to_b1,
    const float* __restrict__ to_w2, const float* __restrict__ to_b2,
    float* __restrict__ out)
{
    int tid = threadIdx.x, lam = tid & 63, wv = tid >> 6;
    int r0 = blockIdx.x*8 + wv*2;              // rows r0, r0+1 (same b,n; t even/odd)
    int b = r0 >> 10, t = r0 & 31;
    // probabilities for both rows: lanes 0-31 row r0, lanes 32-63 row r0+1
    float preg = p_n[r0*32 + lam];
    // neighbor ctx
    float ncA0 = 0.f, ncA1 = 0.f, ncB0 = 0.f, ncB1 = 0.f;
    #pragma unroll
    for (int j = 0; j < 32; ++j) {
        const float* ejA = a_emb + (((b*32+j)*32 + t))*128;
        const float* ejB = ejA + 128;
        float pA = rl(preg, j), pB = rl(preg, 32+j);
        ncA0 = fmaf(pA, ejA[lam],    ncA0);
        ncA1 = fmaf(pA, ejA[64+lam], ncA1);
        ncB0 = fmaf(pB, ejB[lam],    ncB0);
        ncB1 = fmaf(pB, ejB[64+lam], ncB1);
    }
    // tau tables (6 chunks of 64 per row)
    float tA[6], tB[6];
    tA[0] = a_emb[r0*128+lam];       tA[1] = a_emb[r0*128+64+lam];
    tA[2] = map_ctx[r0*128+lam];     tA[3] = map_ctx[r0*128+64+lam];
    tA[4] = ncA0;                    tA[5] = ncA1;
    tB[0] = a_emb[(r0+1)*128+lam];   tB[1] = a_emb[(r0+1)*128+64+lam];
    tB[2] = map_ctx[(r0+1)*128+lam]; tB[3] = map_ctx[(r0+1)*128+64+lam];
    tB[4] = ncB0;                    tB[5] = ncB1;
    // to layer1
    float gA0 = to_b1[lam], gA1 = to_b1[64+lam];
    float gB0 = gA0, gB1 = gA1;
    #pragma unroll
    for (int c = 0; c < 6; ++c) {
        #pragma unroll
        for (int k = 0; k < 64; ++k) {
            float w0 = to_w1[(c*64+k)*128 + lam];
            float w1v = to_w1[(c*64+k)*128 + 64+lam];
            float xA = rl(tA[c], k), xB = rl(tB[c], k);
            gA0 = fmaf(xA, w0, gA0); gA1 = fmaf(xA, w1v, gA1);
            gB0 = fmaf(xB, w0, gB0); gB1 = fmaf(xB, w1v, gB1);
        }
    }
    gA0 = fmaxf(gA0, 0.f); gA1 = fmaxf(gA1, 0.f);
    gB0 = fmaxf(gB0, 0.f); gB1 = fmaxf(gB1, 0.f);
    // to layer2: lane = output o
    float oA = to_b2[lam], oB = oA;
    #pragma unroll
    for (int k = 0; k < 64; ++k) {
        float w = to_w2[k*64 + lam];
        oA = fmaf(rl(gA0, k), w, oA);
        oB = fmaf(rl(gB0, k), w, oB);
    }
    #pragma unroll
    for (int k = 0; k < 64; ++k) {
        float w = to_w2[(64+k)*64 + lam];
        oA = fmaf(rl(gA1, k), w, oA);
        oB = fmaf(rl(gB1, k), w, oB);
    }
    float mkA = (amask[r0]   > 0.5f) ? 1.f : 0.f;
    float mkB = (amask[r0+1] > 0.5f) ? 1.f : 0.f;
    out[r0*64     + lam] = oA * mkA;
    out[(r0+1)*64 + lam] = oB * mkB;
}

extern "C" void kernel_launch(void* const* d_in, const int* in_sizes, int n_in,
                              void* d_out, int out_size, void* d_ws, size_t ws_size,
                              hipStream_t stream) {
    const float* agents_state  = (const float*)d_in[0];
    const float* agents_mask   = (const float*)d_in[1];
    const float* map_polylines = (const float*)d_in[2];
    const float* map_poly_mask = (const float*)d_in[3];
    const int*   map_poly_type = (const int*)d_in[4];
    const int*   map_tl_status = (const int*)d_in[5];
    const int*   map_on_route  = (const int*)d_in[6];
    const float* pm_w1 = (const float*)d_in[7];
    const float* pm_b1 = (const float*)d_in[8];
    const float* pm_w2 = (const float*)d_in[9];
    const float* pm_b2 = (const float*)d_in[10];
    const float* type_emb  = (const float*)d_in[11];
    const float* tl_emb    = (const float*)d_in[12];
    const float* route_emb = (const float*)d_in[13];
    const float* mo_w1 = (const float*)d_in[14];
    const float* mo_b1 = (const float*)d_in[15];
    const float* mo_w2 = (const float*)d_in[16];
    const float* mo_b2 = (const float*)d_in[17];
    const float* ae_w1 = (const float*)d_in[18];
    const float* ae_b1 = (const float*)d_in[19];
    const float* ae_w2 = (const float*)d_in[20];
    const float* ae_b2 = (const float*)d_in[21];
    const float* ae_w3 = (const float*)d_in[22];
    const float* ae_b3 = (const float*)d_in[23];
    const float* mr_w1 = (const float*)d_in[24];
    const float* mr_b1 = (const float*)d_in[25];
    const float* mr_w2 = (const float*)d_in[26];
    const float* mr_b2 = (const float*)d_in[27];
    const float* nr_w1 = (const float*)d_in[28];
    const float* nr_b1 = (const float*)d_in[29];
    const float* nr_w2 = (const float*)d_in[30];
    const float* nr_b2 = (const float*)d_in[31];
    const float* to_w1 = (const float*)d_in[32];
    const float* to_b1 = (const float*)d_in[33];
    const float* to_w2 = (const float*)d_in[34];
    const float* to_b2 = (const float*)d_in[35];

    float* ws = (float*)d_ws;
    float* map_node  = ws;               // 65536
    float* map_nodeT = ws + 65536;       // 65536
    float* cm        = ws + 131072;      // 65536
    float* center    = ws + 196608;      // 1024
    float* a_emb     = ws + 197632;      // 262144
    float* aT        = ws + 459776;      // 262144
    float* q2        = ws + 721920;      // 262144
    float* qn        = ws + 984064;      // 262144
    float* posT      = ws + 1246208;     // 10240
    float* map_ctx   = ws + 1256448;     // 262144
    float* p_n       = ws + 1518592;     // 65536

    float* out = (float*)d_out;

    k_p1<<<640, 256, 0, stream>>>(map_polylines, map_poly_mask,
        map_poly_type, map_tl_status, map_on_route,
        pm_w1, pm_b1, pm_w2, pm_b2, type_emb, tl_emb, route_emb,
        mo_w1, mo_b1, mo_w2, mo_b2, mr_w1, mr_b1,
        agents_state, agents_mask,
        ae_w1, ae_b1, ae_w2, ae_b2, ae_w3, ae_b3,
        nr_w1, nr_b1,
        map_node, map_nodeT, cm, center, a_emb, aT, q2, qn, posT);

    k_p2<<<768, 256, 0, stream>>>(agents_state, map_poly_mask,
        a_emb, map_node, map_nodeT, center, cm,
        mr_w1, mr_w2, mr_b2,
        qn, q2, aT, posT, nr_w1, nr_w2, nr_b2,
        map_ctx, p_n);

    k_p3<<<256, 256, 0, stream>>>(agents_mask, a_emb, map_ctx, p_n,
        to_w1, to_b1, to_w2, to_b2, out);
}

// Round 7
// 227.271 us; speedup vs baseline: 1.7870x; 1.3372x over previous
//
#include <hip/hip_runtime.h>

#define RSQRT_D 0.08838834764831843f

// =====================================================================
// K1: polyline layer-1 elementwise (thread = (row, k)) + poly centers
// rows = B*M*L = 10240, k = 128 -> 1.31M threads
// =====================================================================
__global__ __launch_bounds__(256) void k1_poly(
    const float* __restrict__ poly,
    const float* __restrict__ pm_w1, const float* __restrict__ pm_b1,
    float* __restrict__ h1g, float* __restrict__ center)
{
    int idx = blockIdx.x * 256 + threadIdx.x;
    if (blockIdx.x < 5120) {
        int row = idx >> 7, k = idx & 127;          // row wave-uniform
        float x = poly[row*2], y = poly[row*2+1];   // uniform -> scalar
        h1g[idx] = fmaxf(fmaf(x, pm_w1[k], fmaf(y, pm_w1[128+k], pm_b1[k])), 0.f);
    } else {
        int p = idx - 5120*256;
        if (p < 512) {
            float sx = 0.f, sy = 0.f;
            #pragma unroll
            for (int l = 0; l < 20; ++l) { sx += poly[p*40 + 2*l]; sy += poly[p*40 + 2*l + 1]; }
            center[p*2+0] = sx * 0.05f;
            center[p*2+1] = sy * 0.05f;
        }
    }
}

// =====================================================================
// K2: agent MLP. 512 blocks x 128 thr (thread = h), 4 rows/block.
// Activations via LDS float4 broadcast; weights per-lane coalesced.
// =====================================================================
__global__ __launch_bounds__(128) void k2_agent(
    const float* __restrict__ astate, const float* __restrict__ amask,
    const float* __restrict__ ae_w1, const float* __restrict__ ae_b1,
    const float* __restrict__ ae_w2, const float* __restrict__ ae_b2,
    const float* __restrict__ ae_w3, const float* __restrict__ ae_b3,
    float* __restrict__ a_emb)
{
    int r0 = blockIdx.x * 4;
    int h = threadIdx.x;
    __shared__ float f5[4][5];
    __shared__ __align__(16) float a1s[4][128];
    if (h < 20) f5[h/5][h%5] = astate[(r0 + h/5)*5 + (h%5)];
    __syncthreads();
    float b1v = ae_b1[h];
    float v[4];
    {
        float w0 = ae_w1[h], w1 = ae_w1[128+h], w2 = ae_w1[256+h], w3 = ae_w1[384+h], w4 = ae_w1[512+h];
        #pragma unroll
        for (int r = 0; r < 4; ++r) {
            float a = b1v;
            a = fmaf(f5[r][0], w0, a); a = fmaf(f5[r][1], w1, a);
            a = fmaf(f5[r][2], w2, a); a = fmaf(f5[r][3], w3, a);
            a = fmaf(f5[r][4], w4, a);
            v[r] = fmaxf(a, 0.f);
        }
    }
    #pragma unroll
    for (int r = 0; r < 4; ++r) a1s[r][h] = v[r];
    __syncthreads();
    // layer 2
    {
        float b2v = ae_b2[h];
        float a0 = b2v, a1 = b2v, a2 = b2v, a3 = b2v;
        for (int kc = 0; kc < 32; ++kc) {
            float4 x0 = *(const float4*)&a1s[0][kc*4];
            float4 x1 = *(const float4*)&a1s[1][kc*4];
            float4 x2 = *(const float4*)&a1s[2][kc*4];
            float4 x3 = *(const float4*)&a1s[3][kc*4];
            float w0 = ae_w2[(kc*4+0)*128+h], w1 = ae_w2[(kc*4+1)*128+h];
            float w2 = ae_w2[(kc*4+2)*128+h], w3 = ae_w2[(kc*4+3)*128+h];
            a0 = fmaf(x0.x,w0,fmaf(x0.y,w1,fmaf(x0.z,w2,fmaf(x0.w,w3,a0))));
            a1 = fmaf(x1.x,w0,fmaf(x1.y,w1,fmaf(x1.z,w2,fmaf(x1.w,w3,a1))));
            a2 = fmaf(x2.x,w0,fmaf(x2.y,w1,fmaf(x2.z,w2,fmaf(x2.w,w3,a2))));
            a3 = fmaf(x3.x,w0,fmaf(x3.y,w1,fmaf(x3.z,w2,fmaf(x3.w,w3,a3))));
        }
        v[0]=fmaxf(a0,0.f); v[1]=fmaxf(a1,0.f); v[2]=fmaxf(a2,0.f); v[3]=fmaxf(a3,0.f);
    }
    __syncthreads();
    #pragma unroll
    for (int r = 0; r < 4; ++r) a1s[r][h] = v[r];
    __syncthreads();
    // layer 3
    {
        float b3v = ae_b3[h];
        float a0 = b3v, a1 = b3v, a2 = b3v, a3 = b3v;
        for (int kc = 0; kc < 32; ++kc) {
            float4 x0 = *(const float4*)&a1s[0][kc*4];
            float4 x1 = *(const float4*)&a1s[1][kc*4];
            float4 x2 = *(const float4*)&a1s[2][kc*4];
            float4 x3 = *(const float4*)&a1s[3][kc*4];
            float w0 = ae_w3[(kc*4+0)*128+h], w1 = ae_w3[(kc*4+1)*128+h];
            float w2 = ae_w3[(kc*4+2)*128+h], w3 = ae_w3[(kc*4+3)*128+h];
            a0 = fmaf(x0.x,w0,fmaf(x0.y,w1,fmaf(x0.z,w2,fmaf(x0.w,w3,a0))));
            a1 = fmaf(x1.x,w0,fmaf(x1.y,w1,fmaf(x1.z,w2,fmaf(x1.w,w3,a1))));
            a2 = fmaf(x2.x,w0,fmaf(x2.y,w1,fmaf(x2.z,w2,fmaf(x2.w,w3,a2))));
            a3 = fmaf(x3.x,w0,fmaf(x3.y,w1,fmaf(x3.z,w2,fmaf(x3.w,w3,a3))));
        }
        v[0]=a0; v[1]=a1; v[2]=a2; v[3]=a3;
    }
    #pragma unroll
    for (int r = 0; r < 4; ++r) {
        float mk = (amask[r0+r] > 0.5f) ? 1.f : 0.f;
        a_emb[(r0+r)*128 + h] = v[r] * mk;
    }
}

// =====================================================================
// K3: pm layer-2 + max + embeds + mo MLP. 512 blocks x 128 thr (thread=h).
// h1 via merged s_load (contiguous 16-float chunks); w-tile in VGPRs.
// =====================================================================
__global__ __launch_bounds__(128) void k3_mapnode(
    const float* __restrict__ h1g, const float* __restrict__ pmask,
    const int* __restrict__ ptype, const int* __restrict__ ptl, const int* __restrict__ proute,
    const float* __restrict__ pm_w2, const float* __restrict__ pm_b2,
    const float* __restrict__ type_emb, const float* __restrict__ tl_emb, const float* __restrict__ route_emb,
    const float* __restrict__ mo_w1, const float* __restrict__ mo_b1,
    const float* __restrict__ mo_w2, const float* __restrict__ mo_b2,
    float* __restrict__ map_node, float* __restrict__ map_nodeT)
{
    int bm = blockIdx.x;
    int b = bm >> 8, m = bm & 255;
    int h = threadIdx.x;
    __shared__ __align__(16) float hv[128];
    __shared__ __align__(16) float g2[128];
    float acc[20];
    #pragma unroll
    for (int l = 0; l < 20; ++l) acc[l] = 0.f;
    for (int kc = 0; kc < 8; ++kc) {
        float w[16];
        #pragma unroll
        for (int i = 0; i < 16; ++i) w[i] = pm_w2[(kc*16+i)*128 + h];
        const float* hb = h1g + bm*2560 + kc*16;     // uniform base
        #pragma unroll
        for (int l = 0; l < 20; ++l) {
            const float* xl = hb + l*128;            // 16 contiguous floats -> s_load_dwordx16
            #pragma unroll
            for (int i = 0; i < 16; ++i) acc[l] = fmaf(xl[i], w[i], acc[l]);
        }
    }
    float mx = acc[0];
    #pragma unroll
    for (int l = 1; l < 20; ++l) mx = fmaxf(mx, acc[l]);
    float val = fmaxf(mx + pm_b2[h], 0.f);
    int ti = min(max(ptype[bm],0),3);
    int si = min(max(ptl[bm],0),7);
    int ri = min(max(proute[bm],0),1);
    hv[h] = val + type_emb[ti*128+h] + tl_emb[si*128+h] + route_emb[ri*128+h];
    __syncthreads();
    float a1 = mo_b1[h];
    for (int kc = 0; kc < 32; ++kc) {
        float4 xv = *(const float4*)&hv[kc*4];
        a1 = fmaf(xv.x, mo_w1[(kc*4+0)*128+h],
             fmaf(xv.y, mo_w1[(kc*4+1)*128+h],
             fmaf(xv.z, mo_w1[(kc*4+2)*128+h],
             fmaf(xv.w, mo_w1[(kc*4+3)*128+h], a1))));
    }
    g2[h] = fmaxf(a1, 0.f);
    __syncthreads();
    float a2 = mo_b2[h];
    for (int kc = 0; kc < 32; ++kc) {
        float4 xv = *(const float4*)&g2[kc*4];
        a2 = fmaf(xv.x, mo_w2[(kc*4+0)*128+h],
             fmaf(xv.y, mo_w2[(kc*4+1)*128+h],
             fmaf(xv.z, mo_w2[(kc*4+2)*128+h],
             fmaf(xv.w, mo_w2[(kc*4+3)*128+h], a2))));
    }
    float mk = (pmask[bm] > 0.5f) ? 1.f : 0.f;
    a2 *= mk;
    map_node[bm*128 + h] = a2;
    map_nodeT[(b*128+h)*256 + m] = a2;
}

// =====================================================================
// K4: blocks 0..511  -> map attention (logits+softmax+PV), 4 rows/block
//     blocks 512..767 -> neighbor logits+softmax, 2 rows/wave
// Weights & a_emb rows via contiguous merged s_load; streams via vload.
// =====================================================================
__global__ __launch_bounds__(256) void k4_attn(
    const float* __restrict__ astate, const float* __restrict__ amask,
    const float* __restrict__ pmask,
    const float* __restrict__ a_emb, const float* __restrict__ map_node,
    const float* __restrict__ map_nodeT, const float* __restrict__ center,
    const float* __restrict__ mr_w1, const float* __restrict__ mr_b1,
    const float* __restrict__ mr_w2, const float* __restrict__ mr_b2,
    const float* __restrict__ nr_w1, const float* __restrict__ nr_b1,
    const float* __restrict__ nr_w2, const float* __restrict__ nr_b2,
    float* __restrict__ map_ctx, float* __restrict__ p_n)
{
    int tid = threadIdx.x;
    int lam = tid & 63, wv = tid >> 6;
    __shared__ float lg4[4][256];
    __shared__ __align__(16) float p4[256*4];
    __shared__ float ctxp[4][128];

    if (blockIdx.x < 512) {
        int r0 = blockIdx.x * 4;
        int b = r0 >> 10;
        int m = tid;
        float rx[4], ry[4], dd[4], dt[4], sA[4];
        float b2c = mr_b2[0];
        float cx = center[(b*256+m)*2+0], cy = center[(b*256+m)*2+1];
        #pragma unroll
        for (int r = 0; r < 4; ++r) {
            float px = astate[(r0+r)*5+0], py = astate[(r0+r)*5+1];  // uniform
            rx[r] = cx - px; ry[r] = cy - py;
            dd[r] = sqrtf(rx[r]*rx[r] + ry[r]*ry[r]);
            dt[r] = 0.f; sA[r] = b2c;
        }
        #pragma unroll 8
        for (int hh = 0; hh < 128; ++hh) {
            float wa = mr_w1[hh], wb = mr_w1[128+hh], wc = mr_w1[256+hh];  // merged s_load
            float bb = mr_b1[hh], w2 = mr_w2[hh];
            #pragma unroll
            for (int r = 0; r < 4; ++r) {
                float t1 = fmaf(rx[r], wa, fmaf(ry[r], wb, fmaf(dd[r], wc, bb)));
                sA[r] = fmaf(fmaxf(t1, 0.f), w2, sA[r]);
            }
        }
        const float* mT = map_nodeT + b*128*256 + m;
        #pragma unroll 8
        for (int d = 0; d < 128; ++d) {
            float v = mT[d*256];                                      // coalesced vload
            #pragma unroll
            for (int r = 0; r < 4; ++r)
                dt[r] = fmaf(v, a_emb[(r0+r)*128 + d], dt[r]);        // merged s_load
        }
        bool mk = pmask[b*256+m] > 0.5f;
        #pragma unroll
        for (int r = 0; r < 4; ++r)
            lg4[r][m] = mk ? fmaf(dt[r], RSQRT_D, sA[r]) : -1e30f;
        __syncthreads();
        // softmax: wave wv owns row wv
        {
            float x0 = lg4[wv][lam], x1 = lg4[wv][64+lam], x2 = lg4[wv][128+lam], x3 = lg4[wv][192+lam];
            float mxv = fmaxf(fmaxf(x0,x1), fmaxf(x2,x3));
            #pragma unroll
            for (int off = 32; off; off >>= 1) mxv = fmaxf(mxv, __shfl_xor(mxv, off));
            float e0 = (x0 > -1e29f) ? expf(x0-mxv) : 0.f;
            float e1 = (x1 > -1e29f) ? expf(x1-mxv) : 0.f;
            float e2 = (x2 > -1e29f) ? expf(x2-mxv) : 0.f;
            float e3 = (x3 > -1e29f) ? expf(x3-mxv) : 0.f;
            float sm = e0+e1+e2+e3;
            #pragma unroll
            for (int off = 32; off; off >>= 1) sm += __shfl_xor(sm, off);
            float inv = 1.f / fmaxf(sm, 1e-9f);
            p4[lam*4 + wv]       = e0*inv;
            p4[(64+lam)*4 + wv]  = e1*inv;
            p4[(128+lam)*4 + wv] = e2*inv;
            p4[(192+lam)*4 + wv] = e3*inv;
        }
        __syncthreads();
        // PV: thread d = tid&127, half hf = tid>>7 covers 128 m
        {
            int d = tid & 127, hf = tid >> 7;
            float ac0 = 0.f, ac1 = 0.f, ac2 = 0.f, ac3 = 0.f;
            const float* mn = map_node + (b*256 + hf*128)*128 + d;
            const float4* pp = (const float4*)p4 + hf*128;
            #pragma unroll 4
            for (int mm = 0; mm < 128; ++mm) {
                float4 pv = pp[mm];                 // LDS b128 broadcast
                float v = mn[mm*128];               // coalesced vload
                ac0 = fmaf(pv.x, v, ac0); ac1 = fmaf(pv.y, v, ac1);
                ac2 = fmaf(pv.z, v, ac2); ac3 = fmaf(pv.w, v, ac3);
            }
            if (hf == 1) { ctxp[0][d]=ac0; ctxp[1][d]=ac1; ctxp[2][d]=ac2; ctxp[3][d]=ac3; }
            __syncthreads();
            if (hf == 0) {
                map_ctx[(r0+0)*128+d] = ac0 + ctxp[0][d];
                map_ctx[(r0+1)*128+d] = ac1 + ctxp[1][d];
                map_ctx[(r0+2)*128+d] = ac2 + ctxp[2][d];
                map_ctx[(r0+3)*128+d] = ac3 + ctxp[3][d];
            }
        }
    } else {
        // neighbor: wave = rows (rA, rA+1); half-wave = row, lane-in-half = j
        int rA = (blockIdx.x - 512)*8 + wv*2;
        int hf = lam >> 5, j = lam & 31;
        int r = rA + hf;
        int b = r >> 10, ii = (r >> 5) & 31, tt = r & 31;
        int rj = (b*32 + j)*32 + tt;
        float pxi = astate[r*5+0], pyi = astate[r*5+1], vxi = astate[r*5+3], vyi = astate[r*5+4];
        float pxj = astate[rj*5+0], pyj = astate[rj*5+1], vxj = astate[rj*5+3], vyj = astate[rj*5+4];
        float rpx = pxj-pxi, rpy = pyj-pyi, rvx = vxj-vxi, rvy = vyj-vyi;
        float ddv = sqrtf(rpx*rpx + rpy*rpy);
        float acc = nr_b2[0], dot = 0.f;
        const float* ei = a_emb + (size_t)r*128;
        const float* ej = a_emb + (size_t)rj*128;
        #pragma unroll 8
        for (int hh = 0; hh < 128; ++hh) {
            float wA = nr_w1[hh], wB = nr_w1[128+hh], wC = nr_w1[256+hh];  // merged s_load
            float wD = nr_w1[384+hh], wE = nr_w1[512+hh];
            float bb = nr_b1[hh], w2 = nr_w2[hh];
            float t1 = fmaf(rpx, wA, fmaf(rpy, wB, fmaf(rvx, wC,
                       fmaf(rvy, wD, fmaf(ddv, wE, bb)))));
            acc = fmaf(fmaxf(t1, 0.f), w2, acc);
            dot = fmaf(ei[hh], ej[hh], dot);
        }
        bool vi = amask[r] > 0.5f, vj = amask[rj] > 0.5f;
        bool ok = vi && vj && (ddv <= 30.0f) && (j != ii);
        float lg = ok ? fmaf(dot, RSQRT_D, acc) : -1e30f;
        float mxv = lg;
        #pragma unroll
        for (int off = 16; off; off >>= 1) mxv = fmaxf(mxv, __shfl_xor(mxv, off));
        float e = (lg > -1e29f) ? expf(lg - mxv) : 0.f;
        float sm = e;
        #pragma unroll
        for (int off = 16; off; off >>= 1) sm += __shfl_xor(sm, off);
        p_n[r*32 + j] = e / fmaxf(sm, 1e-9f);
    }
}

// =====================================================================
// K5: neighbor ctx + output MLP. 512 blocks x 256 thr, 4 rows/block.
// Phase E: thread = (h in 0..63 -> outputs h,h+64 ; kq = k-quarter).
// =====================================================================
__global__ __launch_bounds__(256) void k5_out(
    const float* __restrict__ amask, const float* __restrict__ a_emb,
    const float* __restrict__ map_ctx, const float* __restrict__ p_n,
    const float* __restrict__ to_w1, const float* __restrict__ to_b1,
    const float* __restrict__ to_w2, const float* __restrict__ to_b2,
    float* __restrict__ out)
{
    int r0 = blockIdx.x * 4;
    int b = r0 >> 10, t0 = r0 & 31;
    int tid = threadIdx.x;
    __shared__ __align__(16) float tau[4][384];
    __shared__ float redn[4][128];
    __shared__ __align__(16) float gpart[4][4][128];
    __shared__ __align__(16) float g1s[4][128];

    for (int q = tid; q < 512; q += 256) {
        int rr = q >> 7, d = q & 127;
        tau[rr][d]       = a_emb[(r0+rr)*128 + d];
        tau[rr][128 + d] = map_ctx[(r0+rr)*128 + d];
    }
    __syncthreads();
    // Phase D: nbr ctx; thread (d = tid&127, hf = tid>>7), 16 j each
    {
        int d = tid & 127, hf = tid >> 7;
        float ac[4] = {0.f,0.f,0.f,0.f};
        for (int jj = 0; jj < 16; ++jj) {
            int j2 = hf*16 + jj;
            float p0 = p_n[(r0+0)*32 + j2];       // uniform -> merged s_load
            float p1 = p_n[(r0+1)*32 + j2];
            float p2 = p_n[(r0+2)*32 + j2];
            float p3 = p_n[(r0+3)*32 + j2];
            const float* ejb = a_emb + (size_t)((b*32 + j2)*32 + t0)*128 + d;
            ac[0] = fmaf(p0, ejb[0],     ac[0]);
            ac[1] = fmaf(p1, ejb[128],   ac[1]);
            ac[2] = fmaf(p2, ejb[256],   ac[2]);
            ac[3] = fmaf(p3, ejb[384],   ac[3]);
        }
        if (hf == 1) { redn[0][d]=ac[0]; redn[1][d]=ac[1]; redn[2][d]=ac[2]; redn[3][d]=ac[3]; }
        __syncthreads();
        if (hf == 0) {
            #pragma unroll
            for (int r = 0; r < 4; ++r) tau[r][256 + d] = ac[r] + redn[r][d];
        }
    }
    __syncthreads();
    // Phase E: to layer1. thread = (h6 = tid&63, kq = tid>>6); k-range 96.
    {
        int h6 = tid & 63, kq = tid >> 6;
        float aL[4] = {0.f,0.f,0.f,0.f};
        float aH[4] = {0.f,0.f,0.f,0.f};
        for (int c = 0; c < 24; ++c) {
            int k4 = kq*24 + c;
            float4 x0 = *(const float4*)&tau[0][k4*4];
            float4 x1 = *(const float4*)&tau[1][k4*4];
            float4 x2 = *(const float4*)&tau[2][k4*4];
            float4 x3 = *(const float4*)&tau[3][k4*4];
            float wl0 = to_w1[(k4*4+0)*128 + h6],    wh0 = to_w1[(k4*4+0)*128 + 64+h6];
            float wl1 = to_w1[(k4*4+1)*128 + h6],    wh1 = to_w1[(k4*4+1)*128 + 64+h6];
            float wl2 = to_w1[(k4*4+2)*128 + h6],    wh2 = to_w1[(k4*4+2)*128 + 64+h6];
            float wl3 = to_w1[(k4*4+3)*128 + h6],    wh3 = to_w1[(k4*4+3)*128 + 64+h6];
            aL[0]=fmaf(x0.x,wl0,fmaf(x0.y,wl1,fmaf(x0.z,wl2,fmaf(x0.w,wl3,aL[0]))));
            aH[0]=fmaf(x0.x,wh0,fmaf(x0.y,wh1,fmaf(x0.z,wh2,fmaf(x0.w,wh3,aH[0]))));
            aL[1]=fmaf(x1.x,wl0,fmaf(x1.y,wl1,fmaf(x1.z,wl2,fmaf(x1.w,wl3,aL[1]))));
            aH[1]=fmaf(x1.x,wh0,fmaf(x1.y,wh1,fmaf(x1.z,wh2,fmaf(x1.w,wh3,aH[1]))));
            aL[2]=fmaf(x2.x,wl0,fmaf(x2.y,wl1,fmaf(x2.z,wl2,fmaf(x2.w,wl3,aL[2]))));
            aH[2]=fmaf(x2.x,wh0,fmaf(x2.y,wh1,fmaf(x2.z,wh2,fmaf(x2.w,wh3,aH[2]))));
            aL[3]=fmaf(x3.x,wl0,fmaf(x3.y,wl1,fmaf(x3.z,wl2,fmaf(x3.w,wl3,aL[3]))));
            aH[3]=fmaf(x3.x,wh0,fmaf(x3.y,wh1,fmaf(x3.z,wh2,fmaf(x3.w,wh3,aH[3]))));
        }
        #pragma unroll
        for (int r = 0; r < 4; ++r) {
            gpart[kq][r][h6]      = aL[r];
            gpart[kq][r][64 + h6] = aH[r];
        }
    }
    __syncthreads();
    // combine k-quarters + bias + relu
    {
        int h = tid & 127, rp = tid >> 7;
        float bv = to_b1[h];
        #pragma unroll
        for (int rr = rp; rr < 4; rr += 2) {
            float s = gpart[0][rr][h] + gpart[1][rr][h] + gpart[2][rr][h] + gpart[3][rr][h];
            g1s[rr][h] = fmaxf(s + bv, 0.f);
        }
    }
    __syncthreads();
    // Phase F: to layer2; wave = row, lane = output o
    {
        int o = tid & 63, row = tid >> 6;
        float a2 = to_b2[o];
        for (int kc = 0; kc < 32; ++kc) {
            float4 g = *(const float4*)&g1s[row][kc*4];
            a2 = fmaf(g.x, to_w2[(kc*4+0)*64 + o],
                 fmaf(g.y, to_w2[(kc*4+1)*64 + o],
                 fmaf(g.z, to_w2[(kc*4+2)*64 + o],
                 fmaf(g.w, to_w2[(kc*4+3)*64 + o], a2))));
        }
        float mk = (amask[r0+row] > 0.5f) ? 1.f : 0.f;
        out[(r0+row)*64 + o] = a2 * mk;
    }
}

extern "C" void kernel_launch(void* const* d_in, const int* in_sizes, int n_in,
                              void* d_out, int out_size, void* d_ws, size_t ws_size,
                              hipStream_t stream) {
    const float* agents_state  = (const float*)d_in[0];
    const float* agents_mask   = (const float*)d_in[1];
    const float* map_polylines = (const float*)d_in[2];
    const float* map_poly_mask = (const float*)d_in[3];
    const int*   map_poly_type = (const int*)d_in[4];
    const int*   map_tl_status = (const int*)d_in[5];
    const int*   map_on_route  = (const int*)d_in[6];
    const float* pm_w1 = (const float*)d_in[7];
    const float* pm_b1 = (const float*)d_in[8];
    const float* pm_w2 = (const float*)d_in[9];
    const float* pm_b2 = (const float*)d_in[10];
    const float* type_emb  = (const float*)d_in[11];
    const float* tl_emb    = (const float*)d_in[12];
    const float* route_emb = (const float*)d_in[13];
    const float* mo_w1 = (const float*)d_in[14];
    const float* mo_b1 = (const float*)d_in[15];
    const float* mo_w2 = (const float*)d_in[16];
    const float* mo_b2 = (const float*)d_in[17];
    const float* ae_w1 = (const float*)d_in[18];
    const float* ae_b1 = (const float*)d_in[19];
    const float* ae_w2 = (const float*)d_in[20];
    const float* ae_b2 = (const float*)d_in[21];
    const float* ae_w3 = (const float*)d_in[22];
    const float* ae_b3 = (const float*)d_in[23];
    const float* mr_w1 = (const float*)d_in[24];
    const float* mr_b1 = (const float*)d_in[25];
    const float* mr_w2 = (const float*)d_in[26];
    const float* mr_b2 = (const float*)d_in[27];
    const float* nr_w1 = (const float*)d_in[28];
    const float* nr_b1 = (const float*)d_in[29];
    const float* nr_w2 = (const float*)d_in[30];
    const float* nr_b2 = (const float*)d_in[31];
    const float* to_w1 = (const float*)d_in[32];
    const float* to_b1 = (const float*)d_in[33];
    const float* to_w2 = (const float*)d_in[34];
    const float* to_b2 = (const float*)d_in[35];

    float* ws = (float*)d_ws;
    float* h1g       = ws;                 // 10240*128 = 1310720
    float* map_node  = ws + 1310720;       // 65536
    float* map_nodeT = ws + 1376256;       // 65536
    float* center    = ws + 1441792;       // 1024
    float* a_emb     = ws + 1442816;       // 262144
    float* map_ctx   = ws + 1704960;       // 262144
    float* p_n       = ws + 1967104;       // 65536

    float* out = (float*)d_out;

    k1_poly<<<5122, 256, 0, stream>>>(map_polylines, pm_w1, pm_b1, h1g, center);

    k2_agent<<<512, 128, 0, stream>>>(agents_state, agents_mask,
        ae_w1, ae_b1, ae_w2, ae_b2, ae_w3, ae_b3, a_emb);

    k3_mapnode<<<512, 128, 0, stream>>>(h1g, map_poly_mask,
        map_poly_type, map_tl_status, map_on_route,
        pm_w2, pm_b2, type_emb, tl_emb, route_emb,
        mo_w1, mo_b1, mo_w2, mo_b2, map_node, map_nodeT);

    k4_attn<<<768, 256, 0, stream>>>(agents_state, agents_mask, map_poly_mask,
        a_emb, map_node, map_nodeT, center,
        mr_w1, mr_b1, mr_w2, mr_b2,
        nr_w1, nr_b1, nr_w2, nr_b2,
        map_ctx, p_n);

    k5_out<<<512, 256, 0, stream>>>(agents_mask, a_emb, map_ctx, p_n,
        to_w1, to_b1, to_w2, to_b2, out);
}

// Round 8
// 194.238 us; speedup vs baseline: 2.0909x; 1.1701x over previous
//
#include <hip/hip_runtime.h>

#define RSQRT_D 0.08838834764831843f

// =====================================================================
// kA: full map/polyline encoder, one block per (b,m). 256 thr = (h:128, rw:2).
// Layer-1 recomputed in-register per k (K=2!), acc over 10 rows per thread.
// No h1g roundtrip, no unique-data s_load streams in the hot loop.
// =====================================================================
__global__ __launch_bounds__(256) void kA_map(
    const float* __restrict__ poly, const float* __restrict__ pmask,
    const int* __restrict__ ptype, const int* __restrict__ ptl, const int* __restrict__ proute,
    const float* __restrict__ pm_w1, const float* __restrict__ pm_b1,
    const float* __restrict__ pm_w2, const float* __restrict__ pm_b2,
    const float* __restrict__ type_emb, const float* __restrict__ tl_emb, const float* __restrict__ route_emb,
    const float* __restrict__ mo_w1, const float* __restrict__ mo_b1,
    const float* __restrict__ mo_w2, const float* __restrict__ mo_b2,
    float* __restrict__ map_node, float* __restrict__ map_nodeT, float* __restrict__ center)
{
    int bm = blockIdx.x;
    int b = bm >> 8, m = bm & 255;
    int tid = threadIdx.x;
    int h = tid & 127, rw = tid >> 7;
    __shared__ float xch[2][128];
    __shared__ __align__(16) float hvs[128];
    __shared__ __align__(16) float g2[128];

    const float* pp = poly + bm*40 + rw*20;     // rows rw*10..rw*10+9, uniform per wave
    float xs[10], ys[10];
    #pragma unroll
    for (int u = 0; u < 10; ++u) { xs[u] = pp[2*u]; ys[u] = pp[2*u+1]; }
    float acc[10];
    #pragma unroll
    for (int u = 0; u < 10; ++u) acc[u] = 0.f;
    #pragma unroll 4
    for (int k = 0; k < 128; ++k) {
        float w2v = pm_w2[k*128 + h];           // hot vload, coalesced
        float wx = pm_w1[k], wy = pm_w1[128+k], bb = pm_b1[k];   // K$-hot s_load
        #pragma unroll
        for (int u = 0; u < 10; ++u) {
            float h1 = fmaxf(fmaf(wx, xs[u], fmaf(wy, ys[u], bb)), 0.f);
            acc[u] = fmaf(h1, w2v, acc[u]);
        }
    }
    float mx = acc[0];
    #pragma unroll
    for (int u = 1; u < 10; ++u) mx = fmaxf(mx, acc[u]);
    xch[rw][h] = mx;
    __syncthreads();
    if (rw == 0) {
        float v = fmaxf(fmaxf(mx, xch[1][h]) + pm_b2[h], 0.f);  // relu∘max == max∘relu
        int ti = min(max(ptype[bm],0),3);
        int si = min(max(ptl[bm],0),7);
        int ri = min(max(proute[bm],0),1);
        hvs[h] = v + type_emb[ti*128+h] + tl_emb[si*128+h] + route_emb[ri*128+h];
    }
    __syncthreads();
    if (rw == 0) {
        float a1 = mo_b1[h];
        for (int kc = 0; kc < 32; ++kc) {
            float4 xv = *(const float4*)&hvs[kc*4];
            a1 = fmaf(xv.x, mo_w1[(kc*4+0)*128+h],
                 fmaf(xv.y, mo_w1[(kc*4+1)*128+h],
                 fmaf(xv.z, mo_w1[(kc*4+2)*128+h],
                 fmaf(xv.w, mo_w1[(kc*4+3)*128+h], a1))));
        }
        g2[h] = fmaxf(a1, 0.f);
    }
    __syncthreads();
    if (rw == 0) {
        float a2 = mo_b2[h];
        for (int kc = 0; kc < 32; ++kc) {
            float4 xv = *(const float4*)&g2[kc*4];
            a2 = fmaf(xv.x, mo_w2[(kc*4+0)*128+h],
                 fmaf(xv.y, mo_w2[(kc*4+1)*128+h],
                 fmaf(xv.z, mo_w2[(kc*4+2)*128+h],
                 fmaf(xv.w, mo_w2[(kc*4+3)*128+h], a2))));
        }
        float mk = (pmask[bm] > 0.5f) ? 1.f : 0.f;
        a2 *= mk;
        map_node[bm*128 + h] = a2;
        map_nodeT[(b*128+h)*256 + m] = a2;
    }
    if (tid == 0) {
        float sx = 0.f, sy = 0.f;
        #pragma unroll
        for (int l = 0; l < 20; ++l) { sx += poly[bm*40 + 2*l]; sy += poly[bm*40 + 2*l + 1]; }
        center[bm*2+0] = sx * 0.05f;
        center[bm*2+1] = sy * 0.05f;
    }
}

// =====================================================================
// kB: agent MLP (r7 k2) + aT/posT transposed tables for the nbr stage.
// =====================================================================
__global__ __launch_bounds__(128) void kB_agent(
    const float* __restrict__ astate, const float* __restrict__ amask,
    const float* __restrict__ ae_w1, const float* __restrict__ ae_b1,
    const float* __restrict__ ae_w2, const float* __restrict__ ae_b2,
    const float* __restrict__ ae_w3, const float* __restrict__ ae_b3,
    float* __restrict__ a_emb, float* __restrict__ aT, float* __restrict__ posT)
{
    int r0 = blockIdx.x * 4;
    int h = threadIdx.x;
    __shared__ float f5[4][5];
    __shared__ __align__(16) float a1s[4][128];
    if (h < 20) f5[h/5][h%5] = astate[(r0 + h/5)*5 + (h%5)];
    __syncthreads();
    float b1v = ae_b1[h];
    float v[4];
    {
        float w0 = ae_w1[h], w1 = ae_w1[128+h], w2 = ae_w1[256+h], w3 = ae_w1[384+h], w4 = ae_w1[512+h];
        #pragma unroll
        for (int r = 0; r < 4; ++r) {
            float a = b1v;
            a = fmaf(f5[r][0], w0, a); a = fmaf(f5[r][1], w1, a);
            a = fmaf(f5[r][2], w2, a); a = fmaf(f5[r][3], w3, a);
            a = fmaf(f5[r][4], w4, a);
            v[r] = fmaxf(a, 0.f);
        }
    }
    #pragma unroll
    for (int r = 0; r < 4; ++r) a1s[r][h] = v[r];
    __syncthreads();
    {
        float b2v = ae_b2[h];
        float a0 = b2v, a1 = b2v, a2 = b2v, a3 = b2v;
        for (int kc = 0; kc < 32; ++kc) {
            float4 x0 = *(const float4*)&a1s[0][kc*4];
            float4 x1 = *(const float4*)&a1s[1][kc*4];
            float4 x2 = *(const float4*)&a1s[2][kc*4];
            float4 x3 = *(const float4*)&a1s[3][kc*4];
            float w0 = ae_w2[(kc*4+0)*128+h], w1 = ae_w2[(kc*4+1)*128+h];
            float w2 = ae_w2[(kc*4+2)*128+h], w3 = ae_w2[(kc*4+3)*128+h];
            a0 = fmaf(x0.x,w0,fmaf(x0.y,w1,fmaf(x0.z,w2,fmaf(x0.w,w3,a0))));
            a1 = fmaf(x1.x,w0,fmaf(x1.y,w1,fmaf(x1.z,w2,fmaf(x1.w,w3,a1))));
            a2 = fmaf(x2.x,w0,fmaf(x2.y,w1,fmaf(x2.z,w2,fmaf(x2.w,w3,a2))));
            a3 = fmaf(x3.x,w0,fmaf(x3.y,w1,fmaf(x3.z,w2,fmaf(x3.w,w3,a3))));
        }
        v[0]=fmaxf(a0,0.f); v[1]=fmaxf(a1,0.f); v[2]=fmaxf(a2,0.f); v[3]=fmaxf(a3,0.f);
    }
    __syncthreads();
    #pragma unroll
    for (int r = 0; r < 4; ++r) a1s[r][h] = v[r];
    __syncthreads();
    {
        float b3v = ae_b3[h];
        float a0 = b3v, a1 = b3v, a2 = b3v, a3 = b3v;
        for (int kc = 0; kc < 32; ++kc) {
            float4 x0 = *(const float4*)&a1s[0][kc*4];
            float4 x1 = *(const float4*)&a1s[1][kc*4];
            float4 x2 = *(const float4*)&a1s[2][kc*4];
            float4 x3 = *(const float4*)&a1s[3][kc*4];
            float w0 = ae_w3[(kc*4+0)*128+h], w1 = ae_w3[(kc*4+1)*128+h];
            float w2 = ae_w3[(kc*4+2)*128+h], w3 = ae_w3[(kc*4+3)*128+h];
            a0 = fmaf(x0.x,w0,fmaf(x0.y,w1,fmaf(x0.z,w2,fmaf(x0.w,w3,a0))));
            a1 = fmaf(x1.x,w0,fmaf(x1.y,w1,fmaf(x1.z,w2,fmaf(x1.w,w3,a1))));
            a2 = fmaf(x2.x,w0,fmaf(x2.y,w1,fmaf(x2.z,w2,fmaf(x2.w,w3,a2))));
            a3 = fmaf(x3.x,w0,fmaf(x3.y,w1,fmaf(x3.z,w2,fmaf(x3.w,w3,a3))));
        }
        v[0]=a0; v[1]=a1; v[2]=a2; v[3]=a3;
    }
    #pragma unroll
    for (int r = 0; r < 4; ++r) {
        int rr = r0 + r;
        float mk = (amask[rr] > 0.5f) ? 1.f : 0.f;
        float e = v[r] * mk;
        a_emb[rr*128 + h] = e;
        int bb = rr >> 10, nn = (rr >> 5) & 31, tt = rr & 31;
        int bt = bb*32 + tt;
        aT[(bt*128 + h)*32 + nn] = e;
    }
    if (h < 20) {
        int r = h / 5, c = h % 5;
        int rr = r0 + r;
        int bb = rr >> 10, nn = (rr >> 5) & 31, tt = rr & 31;
        int bt = bb*32 + tt;
        float val;
        if      (c == 0) val = f5[r][0];
        else if (c == 1) val = f5[r][1];
        else if (c == 2) val = f5[r][3];
        else if (c == 3) val = f5[r][4];
        else             val = amask[rr];
        posT[(bt*5 + c)*32 + nn] = val;
    }
}

// =====================================================================
// kC: blocks 0..511   -> map attention (logits+softmax+PV), 4 rows/block
//     blocks 512..1023-> neighbor logits+softmax; wave = row, lane = (j, hh-half)
// =====================================================================
__global__ __launch_bounds__(256) void kC_attn(
    const float* __restrict__ astate, const float* __restrict__ amask,
    const float* __restrict__ pmask,
    const float* __restrict__ a_emb, const float* __restrict__ map_node,
    const float* __restrict__ map_nodeT, const float* __restrict__ center,
    const float* __restrict__ mr_w1, const float* __restrict__ mr_b1,
    const float* __restrict__ mr_w2, const float* __restrict__ mr_b2,
    const float* __restrict__ aT, const float* __restrict__ posT,
    const float* __restrict__ nr_w1, const float* __restrict__ nr_b1,
    const float* __restrict__ nr_w2, const float* __restrict__ nr_b2,
    float* __restrict__ map_ctx, float* __restrict__ p_n)
{
    int tid = threadIdx.x;
    int lam = tid & 63, wv = tid >> 6;
    __shared__ float lg4[4][256];
    __shared__ __align__(16) float p4[256*4];
    __shared__ float ctxp[4][128];

    if (blockIdx.x < 512) {
        int r0 = blockIdx.x * 4;
        int b = r0 >> 10;
        int m = tid;
        float rx[4], ry[4], dd[4], dt[4], sA[4];
        float b2c = mr_b2[0];
        float cx = center[(b*256+m)*2+0], cy = center[(b*256+m)*2+1];
        #pragma unroll
        for (int r = 0; r < 4; ++r) {
            float px = astate[(r0+r)*5+0], py = astate[(r0+r)*5+1];
            rx[r] = cx - px; ry[r] = cy - py;
            dd[r] = sqrtf(rx[r]*rx[r] + ry[r]*ry[r]);
            dt[r] = 0.f; sA[r] = b2c;
        }
        #pragma unroll 8
        for (int hh = 0; hh < 128; ++hh) {
            float wa = mr_w1[hh], wb = mr_w1[128+hh], wc = mr_w1[256+hh];
            float bb = mr_b1[hh], w2 = mr_w2[hh];
            #pragma unroll
            for (int r = 0; r < 4; ++r) {
                float t1 = fmaf(rx[r], wa, fmaf(ry[r], wb, fmaf(dd[r], wc, bb)));
                sA[r] = fmaf(fmaxf(t1, 0.f), w2, sA[r]);
            }
        }
        const float* mT = map_nodeT + b*128*256 + m;
        #pragma unroll 8
        for (int d = 0; d < 128; ++d) {
            float v = mT[d*256];
            #pragma unroll
            for (int r = 0; r < 4; ++r)
                dt[r] = fmaf(v, a_emb[(r0+r)*128 + d], dt[r]);
        }
        bool mk = pmask[b*256+m] > 0.5f;
        #pragma unroll
        for (int r = 0; r < 4; ++r)
            lg4[r][m] = mk ? fmaf(dt[r], RSQRT_D, sA[r]) : -1e30f;
        __syncthreads();
        {
            float x0 = lg4[wv][lam], x1 = lg4[wv][64+lam], x2 = lg4[wv][128+lam], x3 = lg4[wv][192+lam];
            float mxv = fmaxf(fmaxf(x0,x1), fmaxf(x2,x3));
            #pragma unroll
            for (int off = 32; off; off >>= 1) mxv = fmaxf(mxv, __shfl_xor(mxv, off));
            float e0 = (x0 > -1e29f) ? expf(x0-mxv) : 0.f;
            float e1 = (x1 > -1e29f) ? expf(x1-mxv) : 0.f;
            float e2 = (x2 > -1e29f) ? expf(x2-mxv) : 0.f;
            float e3 = (x3 > -1e29f) ? expf(x3-mxv) : 0.f;
            float sm = e0+e1+e2+e3;
            #pragma unroll
            for (int off = 32; off; off >>= 1) sm += __shfl_xor(sm, off);
            float inv = 1.f / fmaxf(sm, 1e-9f);
            p4[lam*4 + wv]       = e0*inv;
            p4[(64+lam)*4 + wv]  = e1*inv;
            p4[(128+lam)*4 + wv] = e2*inv;
            p4[(192+lam)*4 + wv] = e3*inv;
        }
        __syncthreads();
        {
            int d = tid & 127, hf = tid >> 7;
            float ac0 = 0.f, ac1 = 0.f, ac2 = 0.f, ac3 = 0.f;
            const float* mn = map_node + (b*256 + hf*128)*128 + d;
            const float4* pp = (const float4*)p4 + hf*128;
            #pragma unroll 4
            for (int mm = 0; mm < 128; ++mm) {
                float4 pv = pp[mm];
                float v = mn[mm*128];
                ac0 = fmaf(pv.x, v, ac0); ac1 = fmaf(pv.y, v, ac1);
                ac2 = fmaf(pv.z, v, ac2); ac3 = fmaf(pv.w, v, ac3);
            }
            if (hf == 1) { ctxp[0][d]=ac0; ctxp[1][d]=ac1; ctxp[2][d]=ac2; ctxp[3][d]=ac3; }
            __syncthreads();
            if (hf == 0) {
                map_ctx[(r0+0)*128+d] = ac0 + ctxp[0][d];
                map_ctx[(r0+1)*128+d] = ac1 + ctxp[1][d];
                map_ctx[(r0+2)*128+d] = ac2 + ctxp[2][d];
                map_ctx[(r0+3)*128+d] = ac3 + ctxp[3][d];
            }
        }
    } else {
        // neighbor: wave = one row r; lane = (j = lam&31, hs = lam>>5 hh-half)
        int r = (blockIdx.x - 512)*4 + wv;
        int b = r >> 10, ii = (r >> 5) & 31, tt = r & 31;
        int bt = b*32 + tt;
        int j = lam & 31, hs = lam >> 5;
        float pxi = astate[r*5+0], pyi = astate[r*5+1], vxi = astate[r*5+3], vyi = astate[r*5+4];
        const float* pT = posT + bt*160;
        float pxj = pT[j], pyj = pT[32+j], vxj = pT[64+j], vyj = pT[96+j], mj = pT[128+j];
        float rpx = pxj-pxi, rpy = pyj-pyi, rvx = vxj-vxi, rvy = vyj-vyi;
        float ddv = sqrtf(rpx*rpx + rpy*rpy);
        const float* ei = a_emb + (size_t)r*128;              // uniform -> s_load
        const float* aTp = aT + (size_t)bt*4096 + j;          // coalesced
        float s = 0.f, dot = 0.f;
        int h0 = hs*64;
        #pragma unroll 8
        for (int q = 0; q < 64; ++q) {
            int hh = h0 + q;
            float wA = nr_w1[hh], wB = nr_w1[128+hh], wC = nr_w1[256+hh];
            float wD = nr_w1[384+hh], wE = nr_w1[512+hh];
            float bb = nr_b1[hh], w2 = nr_w2[hh];
            float t1 = fmaf(rpx, wA, fmaf(rpy, wB, fmaf(rvx, wC,
                       fmaf(rvy, wD, fmaf(ddv, wE, bb)))));
            s = fmaf(fmaxf(t1, 0.f), w2, s);
            dot = fmaf(ei[hh], aTp[hh*32], dot);
        }
        s   += __shfl_xor(s, 32);
        dot += __shfl_xor(dot, 32);
        bool vi = amask[r] > 0.5f, vj = mj > 0.5f;
        bool ok = vi && vj && (ddv <= 30.0f) && (j != ii);
        float lg = ok ? fmaf(dot, RSQRT_D, s + nr_b2[0]) : -1e30f;
        float mxv = lg;
        #pragma unroll
        for (int off = 16; off; off >>= 1) mxv = fmaxf(mxv, __shfl_xor(mxv, off));
        float e = (lg > -1e29f) ? expf(lg - mxv) : 0.f;
        float sm = e;
        #pragma unroll
        for (int off = 16; off; off >>= 1) sm += __shfl_xor(sm, off);
        if (hs == 0) p_n[r*32 + j] = e / fmaxf(sm, 1e-9f);
    }
}

// =====================================================================
// kD: neighbor ctx + output MLP (r7 k5 unchanged).
// =====================================================================
__global__ __launch_bounds__(256) void kD_out(
    const float* __restrict__ amask, const float* __restrict__ a_emb,
    const float* __restrict__ map_ctx, const float* __restrict__ p_n,
    const float* __restrict__ to_w1, const float* __restrict__ to_b1,
    const float* __restrict__ to_w2, const float* __restrict__ to_b2,
    float* __restrict__ out)
{
    int r0 = blockIdx.x * 4;
    int b = r0 >> 10, t0 = r0 & 31;
    int tid = threadIdx.x;
    __shared__ __align__(16) float tau[4][384];
    __shared__ float redn[4][128];
    __shared__ __align__(16) float gpart[4][4][128];
    __shared__ __align__(16) float g1s[4][128];

    for (int q = tid; q < 512; q += 256) {
        int rr = q >> 7, d = q & 127;
        tau[rr][d]       = a_emb[(r0+rr)*128 + d];
        tau[rr][128 + d] = map_ctx[(r0+rr)*128 + d];
    }
    __syncthreads();
    {
        int d = tid & 127, hf = tid >> 7;
        float ac[4] = {0.f,0.f,0.f,0.f};
        for (int jj = 0; jj < 16; ++jj) {
            int j2 = hf*16 + jj;
            float p0 = p_n[(r0+0)*32 + j2];
            float p1 = p_n[(r0+1)*32 + j2];
            float p2 = p_n[(r0+2)*32 + j2];
            float p3 = p_n[(r0+3)*32 + j2];
            const float* ejb = a_emb + (size_t)((b*32 + j2)*32 + t0)*128 + d;
            ac[0] = fmaf(p0, ejb[0],   ac[0]);
            ac[1] = fmaf(p1, ejb[128], ac[1]);
            ac[2] = fmaf(p2, ejb[256], ac[2]);
            ac[3] = fmaf(p3, ejb[384], ac[3]);
        }
        if (hf == 1) { redn[0][d]=ac[0]; redn[1][d]=ac[1]; redn[2][d]=ac[2]; redn[3][d]=ac[3]; }
        __syncthreads();
        if (hf == 0) {
            #pragma unroll
            for (int r = 0; r < 4; ++r) tau[r][256 + d] = ac[r] + redn[r][d];
        }
    }
    __syncthreads();
    {
        int h6 = tid & 63, kq = tid >> 6;
        float aL[4] = {0.f,0.f,0.f,0.f};
        float aH[4] = {0.f,0.f,0.f,0.f};
        for (int c = 0; c < 24; ++c) {
            int k4 = kq*24 + c;
            float4 x0 = *(const float4*)&tau[0][k4*4];
            float4 x1 = *(const float4*)&tau[1][k4*4];
            float4 x2 = *(const float4*)&tau[2][k4*4];
            float4 x3 = *(const float4*)&tau[3][k4*4];
            float wl0 = to_w1[(k4*4+0)*128 + h6], wh0 = to_w1[(k4*4+0)*128 + 64+h6];
            float wl1 = to_w1[(k4*4+1)*128 + h6], wh1 = to_w1[(k4*4+1)*128 + 64+h6];
            float wl2 = to_w1[(k4*4+2)*128 + h6], wh2 = to_w1[(k4*4+2)*128 + 64+h6];
            float wl3 = to_w1[(k4*4+3)*128 + h6], wh3 = to_w1[(k4*4+3)*128 + 64+h6];
            aL[0]=fmaf(x0.x,wl0,fmaf(x0.y,wl1,fmaf(x0.z,wl2,fmaf(x0.w,wl3,aL[0]))));
            aH[0]=fmaf(x0.x,wh0,fmaf(x0.y,wh1,fmaf(x0.z,wh2,fmaf(x0.w,wh3,aH[0]))));
            aL[1]=fmaf(x1.x,wl0,fmaf(x1.y,wl1,fmaf(x1.z,wl2,fmaf(x1.w,wl3,aL[1]))));
            aH[1]=fmaf(x1.x,wh0,fmaf(x1.y,wh1,fmaf(x1.z,wh2,fmaf(x1.w,wh3,aH[1]))));
            aL[2]=fmaf(x2.x,wl0,fmaf(x2.y,wl1,fmaf(x2.z,wl2,fmaf(x2.w,wl3,aL[2]))));
            aH[2]=fmaf(x2.x,wh0,fmaf(x2.y,wh1,fmaf(x2.z,wh2,fmaf(x2.w,wh3,aH[2]))));
            aL[3]=fmaf(x3.x,wl0,fmaf(x3.y,wl1,fmaf(x3.z,wl2,fmaf(x3.w,wl3,aL[3]))));
            aH[3]=fmaf(x3.x,wh0,fmaf(x3.y,wh1,fmaf(x3.z,wh2,fmaf(x3.w,wh3,aH[3]))));
        }
        #pragma unroll
        for (int r = 0; r < 4; ++r) {
            gpart[kq][r][h6]      = aL[r];
            gpart[kq][r][64 + h6] = aH[r];
        }
    }
    __syncthreads();
    {
        int h = tid & 127, rp = tid >> 7;
        float bv = to_b1[h];
        #pragma unroll
        for (int rr = rp; rr < 4; rr += 2) {
            float s = gpart[0][rr][h] + gpart[1][rr][h] + gpart[2][rr][h] + gpart[3][rr][h];
            g1s[rr][h] = fmaxf(s + bv, 0.f);
        }
    }
    __syncthreads();
    {
        int o = tid & 63, row = tid >> 6;
        float a2 = to_b2[o];
        for (int kc = 0; kc < 32; ++kc) {
            float4 g = *(const float4*)&g1s[row][kc*4];
            a2 = fmaf(g.x, to_w2[(kc*4+0)*64 + o],
                 fmaf(g.y, to_w2[(kc*4+1)*64 + o],
                 fmaf(g.z, to_w2[(kc*4+2)*64 + o],
                 fmaf(g.w, to_w2[(kc*4+3)*64 + o], a2))));
        }
        float mk = (amask[r0+row] > 0.5f) ? 1.f : 0.f;
        out[(r0+row)*64 + o] = a2 * mk;
    }
}

extern "C" void kernel_launch(void* const* d_in, const int* in_sizes, int n_in,
                              void* d_out, int out_size, void* d_ws, size_t ws_size,
                              hipStream_t stream) {
    const float* agents_state  = (const float*)d_in[0];
    const float* agents_mask   = (const float*)d_in[1];
    const float* map_polylines = (const float*)d_in[2];
    const float* map_poly_mask = (const float*)d_in[3];
    const int*   map_poly_type = (const int*)d_in[4];
    const int*   map_tl_status = (const int*)d_in[5];
    const int*   map_on_route  = (const int*)d_in[6];
    const float* pm_w1 = (const float*)d_in[7];
    const float* pm_b1 = (const float*)d_in[8];
    const float* pm_w2 = (const float*)d_in[9];
    const float* pm_b2 = (const float*)d_in[10];
    const float* type_emb  = (const float*)d_in[11];
    const float* tl_emb    = (const float*)d_in[12];
    const float* route_emb = (const float*)d_in[13];
    const float* mo_w1 = (const float*)d_in[14];
    const float* mo_b1 = (const float*)d_in[15];
    const float* mo_w2 = (const float*)d_in[16];
    const float* mo_b2 = (const float*)d_in[17];
    const float* ae_w1 = (const float*)d_in[18];
    const float* ae_b1 = (const float*)d_in[19];
    const float* ae_w2 = (const float*)d_in[20];
    const float* ae_b2 = (const float*)d_in[21];
    const float* ae_w3 = (const float*)d_in[22];
    const float* ae_b3 = (const float*)d_in[23];
    const float* mr_w1 = (const float*)d_in[24];
    const float* mr_b1 = (const float*)d_in[25];
    const float* mr_w2 = (const float*)d_in[26];
    const float* mr_b2 = (const float*)d_in[27];
    const float* nr_w1 = (const float*)d_in[28];
    const float* nr_b1 = (const float*)d_in[29];
    const float* nr_w2 = (const float*)d_in[30];
    const float* nr_b2 = (const float*)d_in[31];
    const float* to_w1 = (const float*)d_in[32];
    const float* to_b1 = (const float*)d_in[33];
    const float* to_w2 = (const float*)d_in[34];
    const float* to_b2 = (const float*)d_in[35];

    float* ws = (float*)d_ws;
    float* map_node  = ws;                 // 65536
    float* map_nodeT = ws + 65536;         // 65536
    float* center    = ws + 131072;        // 1024
    float* a_emb     = ws + 132096;        // 262144
    float* aT        = ws + 394240;        // 262144
    float* posT      = ws + 656384;        // 10240
    float* map_ctx   = ws + 666624;        // 262144
    float* p_n       = ws + 928768;        // 65536

    float* out = (float*)d_out;

    kA_map<<<512, 256, 0, stream>>>(map_polylines, map_poly_mask,
        map_poly_type, map_tl_status, map_on_route,
        pm_w1, pm_b1, pm_w2, pm_b2, type_emb, tl_emb, route_emb,
        mo_w1, mo_b1, mo_w2, mo_b2, map_node, map_nodeT, center);

    kB_agent<<<512, 128, 0, stream>>>(agents_state, agents_mask,
        ae_w1, ae_b1, ae_w2, ae_b2, ae_w3, ae_b3, a_emb, aT, posT);

    kC_attn<<<1024, 256, 0, stream>>>(agents_state, agents_mask, map_poly_mask,
        a_emb, map_node, map_nodeT, center,
        mr_w1, mr_b1, mr_w2, mr_b2,
        aT, posT,
        nr_w1, nr_b1, nr_w2, nr_b2,
        map_ctx, p_n);

    kD_out<<<512, 256, 0, stream>>>(agents_mask, a_emb, map_ctx, p_n,
        to_w1, to_b1, to_w2, to_b2, out);
}

// Round 10
// 188.774 us; speedup vs baseline: 2.1515x; 1.0289x over previous
//
#include <hip/hip_runtime.h>

#define RSQRT_D 0.08838834764831843f

// =====================================================================
// kAB: blocks 0..511  -> map/polyline encoder (one block per (b,m))
//      blocks 512..767 -> agent MLP, 256 thr = 2 halves x 4 rows (8 rows/block)
// =====================================================================
__global__ __launch_bounds__(256) void kAB_front(
    const float* __restrict__ poly, const float* __restrict__ pmask,
    const int* __restrict__ ptype, const int* __restrict__ ptl, const int* __restrict__ proute,
    const float* __restrict__ pm_w1, const float* __restrict__ pm_b1,
    const float* __restrict__ pm_w2, const float* __restrict__ pm_b2,
    const float* __restrict__ type_emb, const float* __restrict__ tl_emb, const float* __restrict__ route_emb,
    const float* __restrict__ mo_w1, const float* __restrict__ mo_b1,
    const float* __restrict__ mo_w2, const float* __restrict__ mo_b2,
    const float* __restrict__ astate, const float* __restrict__ amask,
    const float* __restrict__ ae_w1, const float* __restrict__ ae_b1,
    const float* __restrict__ ae_w2, const float* __restrict__ ae_b2,
    const float* __restrict__ ae_w3, const float* __restrict__ ae_b3,
    float* __restrict__ map_node, float* __restrict__ map_nodeT, float* __restrict__ center,
    float* __restrict__ a_emb, float* __restrict__ aT, float* __restrict__ posT)
{
    int tid = threadIdx.x;
    if (blockIdx.x < 512) {
        // ---------------- map/polyline encoder (r8 kA, unchanged) ----------------
        int bm = blockIdx.x;
        int b = bm >> 8, m = bm & 255;
        int h = tid & 127, rw = tid >> 7;
        __shared__ float xch[2][128];
        __shared__ __align__(16) float hvs[128];
        __shared__ __align__(16) float g2[128];

        const float* pp = poly + bm*40 + rw*20;
        float xs[10], ys[10];
        #pragma unroll
        for (int u = 0; u < 10; ++u) { xs[u] = pp[2*u]; ys[u] = pp[2*u+1]; }
        float acc[10];
        #pragma unroll
        for (int u = 0; u < 10; ++u) acc[u] = 0.f;
        #pragma unroll 4
        for (int k = 0; k < 128; ++k) {
            float w2v = pm_w2[k*128 + h];
            float wx = pm_w1[k], wy = pm_w1[128+k], bb = pm_b1[k];
            #pragma unroll
            for (int u = 0; u < 10; ++u) {
                float h1 = fmaxf(fmaf(wx, xs[u], fmaf(wy, ys[u], bb)), 0.f);
                acc[u] = fmaf(h1, w2v, acc[u]);
            }
        }
        float mx = acc[0];
        #pragma unroll
        for (int u = 1; u < 10; ++u) mx = fmaxf(mx, acc[u]);
        xch[rw][h] = mx;
        __syncthreads();
        if (rw == 0) {
            float v = fmaxf(fmaxf(mx, xch[1][h]) + pm_b2[h], 0.f);
            int ti = min(max(ptype[bm],0),3);
            int si = min(max(ptl[bm],0),7);
            int ri = min(max(proute[bm],0),1);
            hvs[h] = v + type_emb[ti*128+h] + tl_emb[si*128+h] + route_emb[ri*128+h];
        }
        __syncthreads();
        if (rw == 0) {
            float a1 = mo_b1[h];
            for (int kc = 0; kc < 32; ++kc) {
                float4 xv = *(const float4*)&hvs[kc*4];
                a1 = fmaf(xv.x, mo_w1[(kc*4+0)*128+h],
                     fmaf(xv.y, mo_w1[(kc*4+1)*128+h],
                     fmaf(xv.z, mo_w1[(kc*4+2)*128+h],
                     fmaf(xv.w, mo_w1[(kc*4+3)*128+h], a1))));
            }
            g2[h] = fmaxf(a1, 0.f);
        }
        __syncthreads();
        if (rw == 0) {
            float a2 = mo_b2[h];
            for (int kc = 0; kc < 32; ++kc) {
                float4 xv = *(const float4*)&g2[kc*4];
                a2 = fmaf(xv.x, mo_w2[(kc*4+0)*128+h],
                     fmaf(xv.y, mo_w2[(kc*4+1)*128+h],
                     fmaf(xv.z, mo_w2[(kc*4+2)*128+h],
                     fmaf(xv.w, mo_w2[(kc*4+3)*128+h], a2))));
            }
            float mk = (pmask[bm] > 0.5f) ? 1.f : 0.f;
            a2 *= mk;
            map_node[bm*128 + h] = a2;
            map_nodeT[(b*128+h)*256 + m] = a2;
        }
        if (tid == 0) {
            float sx = 0.f, sy = 0.f;
            #pragma unroll
            for (int l = 0; l < 20; ++l) { sx += poly[bm*40 + 2*l]; sy += poly[bm*40 + 2*l + 1]; }
            center[bm*2+0] = sx * 0.05f;
            center[bm*2+1] = sy * 0.05f;
        }
    } else {
        // ---------------- agent MLP: 2 halves x 4 rows ----------------
        int h = tid & 127, rp = tid >> 7;
        int r0 = (blockIdx.x - 512)*8 + rp*4;
        __shared__ float f5[2][4][5];
        __shared__ __align__(16) float a1s[2][4][128];
        if (h < 20) f5[rp][h/5][h%5] = astate[(r0 + h/5)*5 + (h%5)];
        __syncthreads();
        float b1v = ae_b1[h];
        float v[4];
        {
            float w0 = ae_w1[h], w1 = ae_w1[128+h], w2 = ae_w1[256+h], w3 = ae_w1[384+h], w4 = ae_w1[512+h];
            #pragma unroll
            for (int r = 0; r < 4; ++r) {
                float a = b1v;
                a = fmaf(f5[rp][r][0], w0, a); a = fmaf(f5[rp][r][1], w1, a);
                a = fmaf(f5[rp][r][2], w2, a); a = fmaf(f5[rp][r][3], w3, a);
                a = fmaf(f5[rp][r][4], w4, a);
                v[r] = fmaxf(a, 0.f);
            }
        }
        #pragma unroll
        for (int r = 0; r < 4; ++r) a1s[rp][r][h] = v[r];
        __syncthreads();
        {
            float b2v = ae_b2[h];
            float a0 = b2v, a1 = b2v, a2 = b2v, a3 = b2v;
            for (int kc = 0; kc < 32; ++kc) {
                float4 x0 = *(const float4*)&a1s[rp][0][kc*4];
                float4 x1 = *(const float4*)&a1s[rp][1][kc*4];
                float4 x2 = *(const float4*)&a1s[rp][2][kc*4];
                float4 x3 = *(const float4*)&a1s[rp][3][kc*4];
                float w0 = ae_w2[(kc*4+0)*128+h], w1 = ae_w2[(kc*4+1)*128+h];
                float w2 = ae_w2[(kc*4+2)*128+h], w3 = ae_w2[(kc*4+3)*128+h];
                a0 = fmaf(x0.x,w0,fmaf(x0.y,w1,fmaf(x0.z,w2,fmaf(x0.w,w3,a0))));
                a1 = fmaf(x1.x,w0,fmaf(x1.y,w1,fmaf(x1.z,w2,fmaf(x1.w,w3,a1))));
                a2 = fmaf(x2.x,w0,fmaf(x2.y,w1,fmaf(x2.z,w2,fmaf(x2.w,w3,a2))));
                a3 = fmaf(x3.x,w0,fmaf(x3.y,w1,fmaf(x3.z,w2,fmaf(x3.w,w3,a3))));
            }
            v[0]=fmaxf(a0,0.f); v[1]=fmaxf(a1,0.f); v[2]=fmaxf(a2,0.f); v[3]=fmaxf(a3,0.f);
        }
        __syncthreads();
        #pragma unroll
        for (int r = 0; r < 4; ++r) a1s[rp][r][h] = v[r];
        __syncthreads();
        {
            float b3v = ae_b3[h];
            float a0 = b3v, a1 = b3v, a2 = b3v, a3 = b3v;
            for (int kc = 0; kc < 32; ++kc) {
                float4 x0 = *(const float4*)&a1s[rp][0][kc*4];
                float4 x1 = *(const float4*)&a1s[rp][1][kc*4];
                float4 x2 = *(const float4*)&a1s[rp][2][kc*4];
                float4 x3 = *(const float4*)&a1s[rp][3][kc*4];
                float w0 = ae_w3[(kc*4+0)*128+h], w1 = ae_w3[(kc*4+1)*128+h];
                float w2 = ae_w3[(kc*4+2)*128+h], w3 = ae_w3[(kc*4+3)*128+h];
                a0 = fmaf(x0.x,w0,fmaf(x0.y,w1,fmaf(x0.z,w2,fmaf(x0.w,w3,a0))));
                a1 = fmaf(x1.x,w0,fmaf(x1.y,w1,fmaf(x1.z,w2,fmaf(x1.w,w3,a1))));
                a2 = fmaf(x2.x,w0,fmaf(x2.y,w1,fmaf(x2.z,w2,fmaf(x2.w,w3,a2))));
                a3 = fmaf(x3.x,w0,fmaf(x3.y,w1,fmaf(x3.z,w2,fmaf(x3.w,w3,a3))));
            }
            v[0]=a0; v[1]=a1; v[2]=a2; v[3]=a3;
        }
        #pragma unroll
        for (int r = 0; r < 4; ++r) {
            int rr = r0 + r;
            float mk = (amask[rr] > 0.5f) ? 1.f : 0.f;
            float e = v[r] * mk;
            a_emb[rr*128 + h] = e;
            int bb = rr >> 10, nn = (rr >> 5) & 31, tt = rr & 31;
            int bt = bb*32 + tt;
            aT[(bt*128 + h)*32 + nn] = e;
        }
        if (h < 20) {
            int r = h / 5, c = h % 5;
            int rr = r0 + r;
            int bb = rr >> 10, nn = (rr >> 5) & 31, tt = rr & 31;
            int bt = bb*32 + tt;
            float val;
            if      (c == 0) val = f5[rp][r][0];
            else if (c == 1) val = f5[rp][r][1];
            else if (c == 2) val = f5[rp][r][3];
            else if (c == 3) val = f5[rp][r][4];
            else             val = amask[rr];
            posT[(bt*5 + c)*32 + nn] = val;
        }
    }
}

// =====================================================================
// kC: blocks 0..511   -> map attention (logits+softmax+PV), 4 rows/block
//     blocks 512..1023-> neighbor logits+softmax; wave = row, lane = (j, hh-half)
// (r8 kC unchanged)
// =====================================================================
__global__ __launch_bounds__(256) void kC_attn(
    const float* __restrict__ astate, const float* __restrict__ amask,
    const float* __restrict__ pmask,
    const float* __restrict__ a_emb, const float* __restrict__ map_node,
    const float* __restrict__ map_nodeT, const float* __restrict__ center,
    const float* __restrict__ mr_w1, const float* __restrict__ mr_b1,
    const float* __restrict__ mr_w2, const float* __restrict__ mr_b2,
    const float* __restrict__ aT, const float* __restrict__ posT,
    const float* __restrict__ nr_w1, const float* __restrict__ nr_b1,
    const float* __restrict__ nr_w2, const float* __restrict__ nr_b2,
    float* __restrict__ map_ctx, float* __restrict__ p_n)
{
    int tid = threadIdx.x;
    int lam = tid & 63, wv = tid >> 6;
    __shared__ float lg4[4][256];
    __shared__ __align__(16) float p4[256*4];
    __shared__ float ctxp[4][128];

    if (blockIdx.x < 512) {
        int r0 = blockIdx.x * 4;
        int b = r0 >> 10;
        int m = tid;
        float rx[4], ry[4], dd[4], dt[4], sA[4];
        float b2c = mr_b2[0];
        float cx = center[(b*256+m)*2+0], cy = center[(b*256+m)*2+1];
        #pragma unroll
        for (int r = 0; r < 4; ++r) {
            float px = astate[(r0+r)*5+0], py = astate[(r0+r)*5+1];
            rx[r] = cx - px; ry[r] = cy - py;
            dd[r] = sqrtf(rx[r]*rx[r] + ry[r]*ry[r]);
            dt[r] = 0.f; sA[r] = b2c;
        }
        #pragma unroll 8
        for (int hh = 0; hh < 128; ++hh) {
            float wa = mr_w1[hh], wb = mr_w1[128+hh], wc = mr_w1[256+hh];
            float bb = mr_b1[hh], w2 = mr_w2[hh];
            #pragma unroll
            for (int r = 0; r < 4; ++r) {
                float t1 = fmaf(rx[r], wa, fmaf(ry[r], wb, fmaf(dd[r], wc, bb)));
                sA[r] = fmaf(fmaxf(t1, 0.f), w2, sA[r]);
            }
        }
        const float* mT = map_nodeT + b*128*256 + m;
        #pragma unroll 8
        for (int d = 0; d < 128; ++d) {
            float v = mT[d*256];
            #pragma unroll
            for (int r = 0; r < 4; ++r)
                dt[r] = fmaf(v, a_emb[(r0+r)*128 + d], dt[r]);
        }
        bool mk = pmask[b*256+m] > 0.5f;
        #pragma unroll
        for (int r = 0; r < 4; ++r)
            lg4[r][m] = mk ? fmaf(dt[r], RSQRT_D, sA[r]) : -1e30f;
        __syncthreads();
        {
            float x0 = lg4[wv][lam], x1 = lg4[wv][64+lam], x2 = lg4[wv][128+lam], x3 = lg4[wv][192+lam];
            float mxv = fmaxf(fmaxf(x0,x1), fmaxf(x2,x3));
            #pragma unroll
            for (int off = 32; off; off >>= 1) mxv = fmaxf(mxv, __shfl_xor(mxv, off));
            float e0 = (x0 > -1e29f) ? expf(x0-mxv) : 0.f;
            float e1 = (x1 > -1e29f) ? expf(x1-mxv) : 0.f;
            float e2 = (x2 > -1e29f) ? expf(x2-mxv) : 0.f;
            float e3 = (x3 > -1e29f) ? expf(x3-mxv) : 0.f;
            float sm = e0+e1+e2+e3;
            #pragma unroll
            for (int off = 32; off; off >>= 1) sm += __shfl_xor(sm, off);
            float inv = 1.f / fmaxf(sm, 1e-9f);
            p4[lam*4 + wv]       = e0*inv;
            p4[(64+lam)*4 + wv]  = e1*inv;
            p4[(128+lam)*4 + wv] = e2*inv;
            p4[(192+lam)*4 + wv] = e3*inv;
        }
        __syncthreads();
        {
            int d = tid & 127, hf = tid >> 7;
            float ac0 = 0.f, ac1 = 0.f, ac2 = 0.f, ac3 = 0.f;
            const float* mn = map_node + (b*256 + hf*128)*128 + d;
            const float4* pp = (const float4*)p4 + hf*128;
            #pragma unroll 4
            for (int mm = 0; mm < 128; ++mm) {
                float4 pv = pp[mm];
                float v = mn[mm*128];
                ac0 = fmaf(pv.x, v, ac0); ac1 = fmaf(pv.y, v, ac1);
                ac2 = fmaf(pv.z, v, ac2); ac3 = fmaf(pv.w, v, ac3);
            }
            if (hf == 1) { ctxp[0][d]=ac0; ctxp[1][d]=ac1; ctxp[2][d]=ac2; ctxp[3][d]=ac3; }
            __syncthreads();
            if (hf == 0) {
                map_ctx[(r0+0)*128+d] = ac0 + ctxp[0][d];
                map_ctx[(r0+1)*128+d] = ac1 + ctxp[1][d];
                map_ctx[(r0+2)*128+d] = ac2 + ctxp[2][d];
                map_ctx[(r0+3)*128+d] = ac3 + ctxp[3][d];
            }
        }
    } else {
        int r = (blockIdx.x - 512)*4 + wv;
        int b = r >> 10, ii = (r >> 5) & 31, tt = r & 31;
        int bt = b*32 + tt;
        int j = lam & 31, hs = lam >> 5;
        float pxi = astate[r*5+0], pyi = astate[r*5+1], vxi = astate[r*5+3], vyi = astate[r*5+4];
        const float* pT = posT + bt*160;
        float pxj = pT[j], pyj = pT[32+j], vxj = pT[64+j], vyj = pT[96+j], mj = pT[128+j];
        float rpx = pxj-pxi, rpy = pyj-pyi, rvx = vxj-vxi, rvy = vyj-vyi;
        float ddv = sqrtf(rpx*rpx + rpy*rpy);
        const float* ei = a_emb + (size_t)r*128;
        const float* aTp = aT + (size_t)bt*4096 + j;
        float s = 0.f, dot = 0.f;
        int h0 = hs*64;
        #pragma unroll 8
        for (int q = 0; q < 64; ++q) {
            int hh = h0 + q;
            float wA = nr_w1[hh], wB = nr_w1[128+hh], wC = nr_w1[256+hh];
            float wD = nr_w1[384+hh], wE = nr_w1[512+hh];
            float bb = nr_b1[hh], w2 = nr_w2[hh];
            float t1 = fmaf(rpx, wA, fmaf(rpy, wB, fmaf(rvx, wC,
                       fmaf(rvy, wD, fmaf(ddv, wE, bb)))));
            s = fmaf(fmaxf(t1, 0.f), w2, s);
            dot = fmaf(ei[hh], aTp[hh*32], dot);
        }
        s   += __shfl_xor(s, 32);
        dot += __shfl_xor(dot, 32);
        bool vi = amask[r] > 0.5f, vj = mj > 0.5f;
        bool ok = vi && vj && (ddv <= 30.0f) && (j != ii);
        float lg = ok ? fmaf(dot, RSQRT_D, s + nr_b2[0]) : -1e30f;
        float mxv = lg;
        #pragma unroll
        for (int off = 16; off; off >>= 1) mxv = fmaxf(mxv, __shfl_xor(mxv, off));
        float e = (lg > -1e29f) ? expf(lg - mxv) : 0.f;
        float sm = e;
        #pragma unroll
        for (int off = 16; off; off >>= 1) sm += __shfl_xor(sm, off);
        if (hs == 0) p_n[r*32 + j] = e / fmaxf(sm, 1e-9f);
    }
}

// =====================================================================
// kD: neighbor ctx + output MLP (r8 kD unchanged).
// =====================================================================
__global__ __launch_bounds__(256) void kD_out(
    const float* __restrict__ amask, const float* __restrict__ a_emb,
    const float* __restrict__ map_ctx, const float* __restrict__ p_n,
    const float* __restrict__ to_w1, const float* __restrict__ to_b1,
    const float* __restrict__ to_w2, const float* __restrict__ to_b2,
    float* __restrict__ out)
{
    int r0 = blockIdx.x * 4;
    int b = r0 >> 10, t0 = r0 & 31;
    int tid = threadIdx.x;
    __shared__ __align__(16) float tau[4][384];
    __shared__ float redn[4][128];
    __shared__ __align__(16) float gpart[4][4][128];
    __shared__ __align__(16) float g1s[4][128];

    for (int q = tid; q < 512; q += 256) {
        int rr = q >> 7, d = q & 127;
        tau[rr][d]       = a_emb[(r0+rr)*128 + d];
        tau[rr][128 + d] = map_ctx[(r0+rr)*128 + d];
    }
    __syncthreads();
    {
        int d = tid & 127, hf = tid >> 7;
        float ac[4] = {0.f,0.f,0.f,0.f};
        for (int jj = 0; jj < 16; ++jj) {
            int j2 = hf*16 + jj;
            float p0 = p_n[(r0+0)*32 + j2];
            float p1 = p_n[(r0+1)*32 + j2];
            float p2 = p_n[(r0+2)*32 + j2];
            float p3 = p_n[(r0+3)*32 + j2];
            const float* ejb = a_emb + (size_t)((b*32 + j2)*32 + t0)*128 + d;
            ac[0] = fmaf(p0, ejb[0],   ac[0]);
            ac[1] = fmaf(p1, ejb[128], ac[1]);
            ac[2] = fmaf(p2, ejb[256], ac[2]);
            ac[3] = fmaf(p3, ejb[384], ac[3]);
        }
        if (hf == 1) { redn[0][d]=ac[0]; redn[1][d]=ac[1]; redn[2][d]=ac[2]; redn[3][d]=ac[3]; }
        __syncthreads();
        if (hf == 0) {
            #pragma unroll
            for (int r = 0; r < 4; ++r) tau[r][256 + d] = ac[r] + redn[r][d];
        }
    }
    __syncthreads();
    {
        int h6 = tid & 63, kq = tid >> 6;
        float aL[4] = {0.f,0.f,0.f,0.f};
        float aH[4] = {0.f,0.f,0.f,0.f};
        for (int c = 0; c < 24; ++c) {
            int k4 = kq*24 + c;
            float4 x0 = *(const float4*)&tau[0][k4*4];
            float4 x1 = *(const float4*)&tau[1][k4*4];
            float4 x2 = *(const float4*)&tau[2][k4*4];
            float4 x3 = *(const float4*)&tau[3][k4*4];
            float wl0 = to_w1[(k4*4+0)*128 + h6], wh0 = to_w1[(k4*4+0)*128 + 64+h6];
            float wl1 = to_w1[(k4*4+1)*128 + h6], wh1 = to_w1[(k4*4+1)*128 + 64+h6];
            float wl2 = to_w1[(k4*4+2)*128 + h6], wh2 = to_w1[(k4*4+2)*128 + 64+h6];
            float wl3 = to_w1[(k4*4+3)*128 + h6], wh3 = to_w1[(k4*4+3)*128 + 64+h6];
            aL[0]=fmaf(x0.x,wl0,fmaf(x0.y,wl1,fmaf(x0.z,wl2,fmaf(x0.w,wl3,aL[0]))));
            aH[0]=fmaf(x0.x,wh0,fmaf(x0.y,wh1,fmaf(x0.z,wh2,fmaf(x0.w,wh3,aH[0]))));
            aL[1]=fmaf(x1.x,wl0,fmaf(x1.y,wl1,fmaf(x1.z,wl2,fmaf(x1.w,wl3,aL[1]))));
            aH[1]=fmaf(x1.x,wh0,fmaf(x1.y,wh1,fmaf(x1.z,wh2,fmaf(x1.w,wh3,aH[1]))));
            aL[2]=fmaf(x2.x,wl0,fmaf(x2.y,wl1,fmaf(x2.z,wl2,fmaf(x2.w,wl3,aL[2]))));
            aH[2]=fmaf(x2.x,wh0,fmaf(x2.y,wh1,fmaf(x2.z,wh2,fmaf(x2.w,wh3,aH[2]))));
            aL[3]=fmaf(x3.x,wl0,fmaf(x3.y,wl1,fmaf(x3.z,wl2,fmaf(x3.w,wl3,aL[3]))));
            aH[3]=fmaf(x3.x,wh0,fmaf(x3.y,wh1,fmaf(x3.z,wh2,fmaf(x3.w,wh3,aH[3]))));
        }
        #pragma unroll
        for (int r = 0; r < 4; ++r) {
            gpart[kq][r][h6]      = aL[r];
            gpart[kq][r][64 + h6] = aH[r];
        }
    }
    __syncthreads();
    {
        int h = tid & 127, rp = tid >> 7;
        float bv = to_b1[h];
        #pragma unroll
        for (int rr = rp; rr < 4; rr += 2) {
            float s = gpart[0][rr][h] + gpart[1][rr][h] + gpart[2][rr][h] + gpart[3][rr][h];
            g1s[rr][h] = fmaxf(s + bv, 0.f);
        }
    }
    __syncthreads();
    {
        int o = tid & 63, row = tid >> 6;
        float a2 = to_b2[o];
        for (int kc = 0; kc < 32; ++kc) {
            float4 g = *(const float4*)&g1s[row][kc*4];
            a2 = fmaf(g.x, to_w2[(kc*4+0)*64 + o],
                 fmaf(g.y, to_w2[(kc*4+1)*64 + o],
                 fmaf(g.z, to_w2[(kc*4+2)*64 + o],
                 fmaf(g.w, to_w2[(kc*4+3)*64 + o], a2))));
        }
        float mk = (amask[r0+row] > 0.5f) ? 1.f : 0.f;
        out[(r0+row)*64 + o] = a2 * mk;
    }
}

extern "C" void kernel_launch(void* const* d_in, const int* in_sizes, int n_in,
                              void* d_out, int out_size, void* d_ws, size_t ws_size,
                              hipStream_t stream) {
    const float* agents_state  = (const float*)d_in[0];
    const float* agents_mask   = (const float*)d_in[1];
    const float* map_polylines = (const float*)d_in[2];
    const float* map_poly_mask = (const float*)d_in[3];
    const int*   map_poly_type = (const int*)d_in[4];
    const int*   map_tl_status = (const int*)d_in[5];
    const int*   map_on_route  = (const int*)d_in[6];
    const float* pm_w1 = (const float*)d_in[7];
    const float* pm_b1 = (const float*)d_in[8];
    const float* pm_w2 = (const float*)d_in[9];
    const float* pm_b2 = (const float*)d_in[10];
    const float* type_emb  = (const float*)d_in[11];
    const float* tl_emb    = (const float*)d_in[12];
    const float* route_emb = (const float*)d_in[13];
    const float* mo_w1 = (const float*)d_in[14];
    const float* mo_b1 = (const float*)d_in[15];
    const float* mo_w2 = (const float*)d_in[16];
    const float* mo_b2 = (const float*)d_in[17];
    const float* ae_w1 = (const float*)d_in[18];
    const float* ae_b1 = (const float*)d_in[19];
    const float* ae_w2 = (const float*)d_in[20];
    const float* ae_b2 = (const float*)d_in[21];
    const float* ae_w3 = (const float*)d_in[22];
    const float* ae_b3 = (const float*)d_in[23];
    const float* mr_w1 = (const float*)d_in[24];
    const float* mr_b1 = (const float*)d_in[25];
    const float* mr_w2 = (const float*)d_in[26];
    const float* mr_b2 = (const float*)d_in[27];
    const float* nr_w1 = (const float*)d_in[28];
    const float* nr_b1 = (const float*)d_in[29];
    const float* nr_w2 = (const float*)d_in[30];
    const float* nr_b2 = (const float*)d_in[31];
    const float* to_w1 = (const float*)d_in[32];
    const float* to_b1 = (const float*)d_in[33];
    const float* to_w2 = (const float*)d_in[34];
    const float* to_b2 = (const float*)d_in[35];

    float* ws = (float*)d_ws;
    float* map_node  = ws;                 // 65536
    float* map_nodeT = ws + 65536;         // 65536
    float* center    = ws + 131072;        // 1024
    float* a_emb     = ws + 132096;        // 262144
    float* aT        = ws + 394240;        // 262144
    float* posT      = ws + 656384;        // 10240
    float* map_ctx   = ws + 666624;        // 262144
    float* p_n       = ws + 928768;        // 65536

    float* out = (float*)d_out;

    kAB_front<<<768, 256, 0, stream>>>(map_polylines, map_poly_mask,
        map_poly_type, map_tl_status, map_on_route,
        pm_w1, pm_b1, pm_w2, pm_b2, type_emb, tl_emb, route_emb,
        mo_w1, mo_b1, mo_w2, mo_b2,
        agents_state, agents_mask,
        ae_w1, ae_b1, ae_w2, ae_b2, ae_w3, ae_b3,
        map_node, map_nodeT, center, a_emb, aT, posT);

    kC_attn<<<1024, 256, 0, stream>>>(agents_state, agents_mask, map_poly_mask,
        a_emb, map_node, map_nodeT, center,
        mr_w1, mr_b1, mr_w2, mr_b2,
        aT, posT,
        nr_w1, nr_b1, nr_w2, nr_b2,
        map_ctx, p_n);

    kD_out<<<512, 256, 0, stream>>>(agents_mask, a_emb, map_ctx, p_n,
        to_w1, to_b1, to_w2, to_b2, out);
}